// Round 9
// baseline (463.584 us; speedup 1.0000x reference)
//
#include <hip/hip_runtime.h>
#include <hip/hip_fp16.h>

// ---------------------------------------------------------------------------
// GIN forward (eval mode), fp16-MFMA version.
// prep: fold BN into weights, transpose to [n][k] f16.
// CSR build XCD-range-partitioned (dst-range bid&7), esrc u16.
// per layer: lin_mfma (h -> h2, MFMA+relu)
//            -> aggmlp (fused: CSR gather-sum of h2 into LDS A-tile,
//               then GEMM1(relu)+GEMM2; last layer: readout dot +
//               segmented-scan graph reduce). No z buffer round-trip.
// ---------------------------------------------------------------------------

#define HD 128
#define NLAYER 3
#define PITCH 136   // f16 units per LDS row (272 B = 17 x 16 B chunks)
#define EPB 2048    // edges per (chunk) block in CSR build

typedef _Float16 half8 __attribute__((ext_vector_type(8)));
typedef _Float16 half2f __attribute__((ext_vector_type(2)));
typedef float    f32x4 __attribute__((ext_vector_type(4)));

// ---------------- prep: fold BN, convert + transpose weights to f16 --------
__global__ void prep_weights(
    const float* __restrict__ bn_g, const float* __restrict__ bn_b,
    const float* __restrict__ bn_m, const float* __restrict__ bn_v,
    const float* __restrict__ lin_w, const float* __restrict__ lin_b,
    const float* __restrict__ mbn_g, const float* __restrict__ mbn_b,
    const float* __restrict__ mbn_m, const float* __restrict__ mbn_v,
    const float* __restrict__ mlp_w1, const float* __restrict__ mlp_b1,
    const float* __restrict__ mlp_w2,
    _Float16* __restrict__ wtl, float* __restrict__ fbl,
    _Float16* __restrict__ wt1, float* __restrict__ fb1,
    _Float16* __restrict__ wt2)
{
    const int l = blockIdx.x;
    const int t = threadIdx.x;          // 128 threads
    __shared__ float sa[HD], sc[HD], sa2[HD];

    const int lb = l * HD;
    const int wb = l * HD * HD;
    float a  = bn_g[lb + t] * rsqrtf(bn_v[lb + t] + 1e-5f);
    float c  = bn_b[lb + t] - bn_m[lb + t] * a;
    float a2 = mbn_g[lb + t] * rsqrtf(mbn_v[lb + t] + 1e-5f);
    float c2 = mbn_b[lb + t] - mbn_m[lb + t] * a2;
    sa[t] = a; sc[t] = c; sa2[t] = a2;
    __syncthreads();

    float accb = lin_b[lb + t];
    for (int k = 0; k < HD; ++k) accb += sc[k] * lin_w[wb + k * HD + t];
    fbl[lb + t] = accb;
    fb1[lb + t] = a2 * mlp_b1[lb + t] + c2;

    // transposed f16 weights: Wt[j][k]; thread t = k, loop j -> coalesced writes
    for (int j = 0; j < HD; ++j) {
        wtl[wb + j * HD + t] = (_Float16)(sa[t] * lin_w[wb + t * HD + j]);
        wt1[wb + j * HD + t] = (_Float16)(sa2[j] * mlp_w1[wb + t * HD + j]);
        wt2[wb + j * HD + t] = (_Float16)(mlp_w2[wb + t * HD + j]);
    }
}

// ---------------- CSR build (XCD-range partitioned) ----------------
__global__ void count_deg(const int* __restrict__ dst, int* __restrict__ deg,
                          int e, int npr)
{
    int r = blockIdx.x & 7;
    int chunk = blockIdx.x >> 3;
    int lo = r * npr, hi = lo + npr;
    int base = chunk * EPB;
    int end = base + EPB; if (end > e) end = e;
    for (int i = base + threadIdx.x; i < end; i += 256) {
        int d = dst[i];
        if (d >= lo && d < hi) atomicAdd(&deg[d], 1);
    }
}

__global__ void fill_csr(const int* __restrict__ src, const int* __restrict__ dst,
                         int* __restrict__ cursor,
                         unsigned short* __restrict__ esrc, int e, int npr)
{
    int r = blockIdx.x & 7;
    int chunk = blockIdx.x >> 3;
    int lo = r * npr, hi = lo + npr;
    int base = chunk * EPB;
    int end = base + EPB; if (end > e) end = e;
    for (int i = base + threadIdx.x; i < end; i += 256) {
        int d = dst[i];
        int s = src[i];
        if (d >= lo && d < hi) {
            int p = atomicAdd(&cursor[d], 1);
            esrc[p] = (unsigned short)s;
        }
    }
}

__global__ void scan_blocks(const int* __restrict__ deg, int* __restrict__ excl,
                            int* __restrict__ partials, int n)
{
    __shared__ int wt[4];
    int t = threadIdx.x;
    int base = blockIdx.x * 1024 + t * 4;
    int v0 = (base + 0 < n) ? deg[base + 0] : 0;
    int v1 = (base + 1 < n) ? deg[base + 1] : 0;
    int v2 = (base + 2 < n) ? deg[base + 2] : 0;
    int v3 = (base + 3 < n) ? deg[base + 3] : 0;
    int s = v0 + v1 + v2 + v3;
    int lane = t & 63, w = t >> 6;
    int inc = s;
    #pragma unroll
    for (int d = 1; d < 64; d <<= 1) {
        int o = __shfl_up(inc, d);
        if (lane >= d) inc += o;
    }
    if (lane == 63) wt[w] = inc;
    __syncthreads();
    int off = 0;
    for (int i = 0; i < w; ++i) off += wt[i];
    int ex = off + inc - s;
    if (base + 0 < n) excl[base + 0] = ex; ex += v0;
    if (base + 1 < n) excl[base + 1] = ex; ex += v1;
    if (base + 2 < n) excl[base + 2] = ex; ex += v2;
    if (base + 3 < n) excl[base + 3] = ex;
    if (t == 255) partials[blockIdx.x] = off + inc;
}

__global__ void scan_small(int* __restrict__ partials, int nb)
{
    int t = threadIdx.x;
    int v = (t < nb) ? partials[t] : 0;
    int inc = v;
    #pragma unroll
    for (int d = 1; d < 64; d <<= 1) {
        int o = __shfl_up(inc, d);
        if (t >= d) inc += o;
    }
    if (t < nb) partials[t] = inc - v;
}

__global__ void scan_add(int* __restrict__ rowst, int* __restrict__ cursor,
                         const int* __restrict__ partials, int n, int e)
{
    int idx = blockIdx.x * blockDim.x + threadIdx.x;
    if (idx < n) {
        int v = rowst[idx] + partials[idx >> 10];
        rowst[idx] = v;
        cursor[idx] = v;
    }
    if (idx == 0) rowst[n] = e;
}

// ---------------- lin_mfma: H2 = relu(X @ W + B) -> f16 --------------------
template<bool GATHER>
__global__ __launch_bounds__(256, 3)
void lin_mfma(const float* __restrict__ Xf, const _Float16* __restrict__ Xh,
              const int* __restrict__ xidx,
              const _Float16* __restrict__ Wt, const float* __restrict__ B,
              _Float16* __restrict__ Y, int n)
{
    __shared__ __align__(16) _Float16 sA[64 * PITCH];
    const int t = threadIdx.x;
    const int lane = t & 63;
    const int w = t >> 6;
    const int rw_ = w >> 1, cw = w & 1;
    const int m = lane & 15, g = lane >> 4;
    const int tile = blockIdx.x * 64;

    {
        int row = t >> 2, q = t & 3;
        int gr = tile + row;
        _Float16* dst = &sA[row * PITCH + q * 32];
        if (GATHER) {
            if (gr < n) {
                int id = xidx[gr];
                const float4* src = reinterpret_cast<const float4*>(Xf + (size_t)id * HD) + q * 8;
                #pragma unroll
                for (int c = 0; c < 4; ++c) {
                    float4 va = src[2 * c], vb = src[2 * c + 1];
                    half8 h = {(_Float16)va.x, (_Float16)va.y, (_Float16)va.z, (_Float16)va.w,
                               (_Float16)vb.x, (_Float16)vb.y, (_Float16)vb.z, (_Float16)vb.w};
                    *reinterpret_cast<half8*>(dst + c * 8) = h;
                }
            } else {
                half8 zz = {0, 0, 0, 0, 0, 0, 0, 0};
                #pragma unroll
                for (int c = 0; c < 4; ++c) *reinterpret_cast<half8*>(dst + c * 8) = zz;
            }
        } else {
            half8 zz = {0, 0, 0, 0, 0, 0, 0, 0};
            const half8* src = reinterpret_cast<const half8*>(Xh + (size_t)gr * HD + q * 32);
            #pragma unroll
            for (int c = 0; c < 4; ++c)
                *reinterpret_cast<half8*>(dst + c * 8) = (gr < n) ? src[c] : zz;
        }
    }
    __syncthreads();

    half8 bf[4][4];
    #pragma unroll
    for (int ct4 = 0; ct4 < 4; ++ct4) {
        int ct = 4 * cw + ct4;
        #pragma unroll
        for (int kk = 0; kk < 4; ++kk)
            bf[ct4][kk] = *reinterpret_cast<const half8*>(
                Wt + (size_t)(16 * ct + m) * HD + kk * 32 + g * 8);
    }

    f32x4 acc[2][4];
    #pragma unroll
    for (int i = 0; i < 2; ++i)
        #pragma unroll
        for (int j = 0; j < 4; ++j) acc[i][j] = (f32x4){0.f, 0.f, 0.f, 0.f};

    #pragma unroll
    for (int rg2 = 0; rg2 < 2; ++rg2) {
        int rg = 2 * rw_ + rg2;
        #pragma unroll
        for (int kk = 0; kk < 4; ++kk) {
            half8 a = *reinterpret_cast<const half8*>(
                &sA[(16 * rg + m) * PITCH + kk * 32 + g * 8]);
            #pragma unroll
            for (int ct4 = 0; ct4 < 4; ++ct4)
                acc[rg2][ct4] = __builtin_amdgcn_mfma_f32_16x16x32_f16(
                    a, bf[ct4][kk], acc[rg2][ct4], 0, 0, 0);
        }
    }

    #pragma unroll
    for (int rg2 = 0; rg2 < 2; ++rg2) {
        int rg = 2 * rw_ + rg2;
        #pragma unroll
        for (int ct4 = 0; ct4 < 4; ++ct4) {
            int col = 16 * (4 * cw + ct4) + m;
            float bb = B[col];
            #pragma unroll
            for (int reg = 0; reg < 4; ++reg) {
                int r = tile + 16 * rg + 4 * g + reg;
                if (r < n) {
                    float v = fmaxf(acc[rg2][ct4][reg] + bb, 0.f);
                    Y[(size_t)r * HD + col] = (_Float16)v;
                }
            }
        }
    }
}

// ---------------- aggmlp: fused aggregate + MLP ---------------------------
// Gather phase: wave w sums rows [16w,16w+16) of the tile directly into the
// LDS A-tile ((1+eps)*own + sum of in-edge h2 rows; f32 accum, 8-deep ILP,
// f16 half2 LDS store). Then GEMM1(relu) + GEMM2 as before.
template<bool FUSE_RO>
__global__ __launch_bounds__(256, 3)
void aggmlp(const _Float16* __restrict__ h2,
            const int* __restrict__ rowst, const unsigned short* __restrict__ esrc,
            const float* __restrict__ epsp, int layer,
            const _Float16* __restrict__ Wt1, const float* __restrict__ B1,
            const _Float16* __restrict__ Wt2, const float* __restrict__ B2,
            _Float16* __restrict__ H,
            const float* __restrict__ rw, const float* __restrict__ rb,
            const int* __restrict__ batch, float* __restrict__ gout, int n)
{
    __shared__ __align__(16) _Float16 sA[64 * PITCH];
    __shared__ float sD[64][2];
    const int t = threadIdx.x;
    const int lane = t & 63;
    const int w = t >> 6;
    const int rw_ = w >> 1, cw = w & 1;
    const int m = lane & 15, g = lane >> 4;
    const int tile = blockIdx.x * 64;

    // ---- gather phase ----
    {
        const half2* hv = reinterpret_cast<const half2*>(h2);
        const float se = 1.0f + epsp[layer];
        for (int rr = 0; rr < 16; ++rr) {
            int node = tile + 16 * w + rr;
            float ox = 0.f, oy = 0.f;
            if (node < n) {
                int rs = __builtin_amdgcn_readfirstlane(rowst[node]);
                int re = __builtin_amdgcn_readfirstlane(rowst[node + 1]);
                float2 own = __half22float2(hv[(size_t)node * 64 + lane]);
                float ax0 = se * own.x, ay0 = se * own.y;
                float ax1 = 0.f, ay1 = 0.f, ax2 = 0.f, ay2 = 0.f, ax3 = 0.f, ay3 = 0.f;
                float ax4 = 0.f, ay4 = 0.f, ax5 = 0.f, ay5 = 0.f, ax6 = 0.f, ay6 = 0.f, ax7 = 0.f, ay7 = 0.f;
                for (int base = rs; base < re; base += 64) {
                    int cnt = re - base; if (cnt > 64) cnt = 64;
                    int eid = (base + lane < re) ? (int)esrc[base + lane] : 0;
                    int j = 0;
                    for (; j + 8 <= cnt; j += 8) {
                        int s0 = __shfl(eid, j + 0);
                        int s1 = __shfl(eid, j + 1);
                        int s2 = __shfl(eid, j + 2);
                        int s3 = __shfl(eid, j + 3);
                        int s4 = __shfl(eid, j + 4);
                        int s5 = __shfl(eid, j + 5);
                        int s6 = __shfl(eid, j + 6);
                        int s7 = __shfl(eid, j + 7);
                        float2 v0 = __half22float2(hv[(size_t)s0 * 64 + lane]);
                        float2 v1 = __half22float2(hv[(size_t)s1 * 64 + lane]);
                        float2 v2 = __half22float2(hv[(size_t)s2 * 64 + lane]);
                        float2 v3 = __half22float2(hv[(size_t)s3 * 64 + lane]);
                        float2 v4 = __half22float2(hv[(size_t)s4 * 64 + lane]);
                        float2 v5 = __half22float2(hv[(size_t)s5 * 64 + lane]);
                        float2 v6 = __half22float2(hv[(size_t)s6 * 64 + lane]);
                        float2 v7 = __half22float2(hv[(size_t)s7 * 64 + lane]);
                        ax0 += v0.x; ay0 += v0.y;  ax1 += v1.x; ay1 += v1.y;
                        ax2 += v2.x; ay2 += v2.y;  ax3 += v3.x; ay3 += v3.y;
                        ax4 += v4.x; ay4 += v4.y;  ax5 += v5.x; ay5 += v5.y;
                        ax6 += v6.x; ay6 += v6.y;  ax7 += v7.x; ay7 += v7.y;
                    }
                    for (; j < cnt; ++j) {
                        int s0 = __shfl(eid, j);
                        float2 v0 = __half22float2(hv[(size_t)s0 * 64 + lane]);
                        ax0 += v0.x; ay0 += v0.y;
                    }
                }
                ox = ((ax0 + ax1) + (ax2 + ax3)) + ((ax4 + ax5) + (ax6 + ax7));
                oy = ((ay0 + ay1) + (ay2 + ay3)) + ((ay4 + ay5) + (ay6 + ay7));
            }
            *reinterpret_cast<half2f*>(&sA[(16 * w + rr) * PITCH + 2 * lane]) =
                (half2f){(_Float16)ox, (_Float16)oy};
        }
    }
    __syncthreads();

    // ---- GEMM1 ----
    half8 bf[4][4];
    #pragma unroll
    for (int ct4 = 0; ct4 < 4; ++ct4) {
        int ct = 4 * cw + ct4;
        #pragma unroll
        for (int kk = 0; kk < 4; ++kk)
            bf[ct4][kk] = *reinterpret_cast<const half8*>(
                Wt1 + (size_t)(16 * ct + m) * HD + kk * 32 + g * 8);
    }
    f32x4 acc[2][4];
    #pragma unroll
    for (int i = 0; i < 2; ++i)
        #pragma unroll
        for (int j = 0; j < 4; ++j) acc[i][j] = (f32x4){0.f, 0.f, 0.f, 0.f};
    #pragma unroll
    for (int rg2 = 0; rg2 < 2; ++rg2) {
        int rg = 2 * rw_ + rg2;
        #pragma unroll
        for (int kk = 0; kk < 4; ++kk) {
            half8 a = *reinterpret_cast<const half8*>(
                &sA[(16 * rg + m) * PITCH + kk * 32 + g * 8]);
            #pragma unroll
            for (int ct4 = 0; ct4 < 4; ++ct4)
                acc[rg2][ct4] = __builtin_amdgcn_mfma_f32_16x16x32_f16(
                    a, bf[ct4][kk], acc[rg2][ct4], 0, 0, 0);
        }
    }
    __syncthreads();

    // ---- z2 = relu(acc + B1) scattered back into sA ----
    #pragma unroll
    for (int rg2 = 0; rg2 < 2; ++rg2) {
        int rg = 2 * rw_ + rg2;
        #pragma unroll
        for (int ct4 = 0; ct4 < 4; ++ct4) {
            int col = 16 * (4 * cw + ct4) + m;
            float bb = B1[col];
            #pragma unroll
            for (int reg = 0; reg < 4; ++reg) {
                int lr = 16 * rg + 4 * g + reg;
                sA[lr * PITCH + col] = (_Float16)fmaxf(acc[rg2][ct4][reg] + bb, 0.f);
            }
        }
    }
    __syncthreads();

    // ---- GEMM2 ----
    #pragma unroll
    for (int ct4 = 0; ct4 < 4; ++ct4) {
        int ct = 4 * cw + ct4;
        #pragma unroll
        for (int kk = 0; kk < 4; ++kk)
            bf[ct4][kk] = *reinterpret_cast<const half8*>(
                Wt2 + (size_t)(16 * ct + m) * HD + kk * 32 + g * 8);
    }
    f32x4 acc2[2][4];
    #pragma unroll
    for (int i = 0; i < 2; ++i)
        #pragma unroll
        for (int j = 0; j < 4; ++j) acc2[i][j] = (f32x4){0.f, 0.f, 0.f, 0.f};
    #pragma unroll
    for (int rg2 = 0; rg2 < 2; ++rg2) {
        int rg = 2 * rw_ + rg2;
        #pragma unroll
        for (int kk = 0; kk < 4; ++kk) {
            half8 a = *reinterpret_cast<const half8*>(
                &sA[(16 * rg + m) * PITCH + kk * 32 + g * 8]);
            #pragma unroll
            for (int ct4 = 0; ct4 < 4; ++ct4)
                acc2[rg2][ct4] = __builtin_amdgcn_mfma_f32_16x16x32_f16(
                    a, bf[ct4][kk], acc2[rg2][ct4], 0, 0, 0);
        }
    }

    if (!FUSE_RO) {
        #pragma unroll
        for (int rg2 = 0; rg2 < 2; ++rg2) {
            int rg = 2 * rw_ + rg2;
            #pragma unroll
            for (int ct4 = 0; ct4 < 4; ++ct4) {
                int col = 16 * (4 * cw + ct4) + m;
                float bb = B2[col];
                #pragma unroll
                for (int reg = 0; reg < 4; ++reg) {
                    int r = tile + 16 * rg + 4 * g + reg;
                    if (r < n)
                        H[(size_t)r * HD + col] = (_Float16)(acc2[rg2][ct4][reg] + bb);
                }
            }
        }
    } else {
        #pragma unroll
        for (int rg2 = 0; rg2 < 2; ++rg2) {
            int rg = 2 * rw_ + rg2;
            float pr[4] = {0.f, 0.f, 0.f, 0.f};
            #pragma unroll
            for (int ct4 = 0; ct4 < 4; ++ct4) {
                int col = 16 * (4 * cw + ct4) + m;
                float bb = B2[col], rr = rw[col];
                #pragma unroll
                for (int reg = 0; reg < 4; ++reg)
                    pr[reg] = fmaf(acc2[rg2][ct4][reg] + bb, rr, pr[reg]);
            }
            #pragma unroll
            for (int reg = 0; reg < 4; ++reg) {
                #pragma unroll
                for (int d = 1; d < 16; d <<= 1) pr[reg] += __shfl_xor(pr[reg], d);
            }
            if (m == 0) {
                #pragma unroll
                for (int reg = 0; reg < 4; ++reg)
                    sD[16 * rg + 4 * g + reg][cw] = pr[reg];
            }
        }
        __syncthreads();
        if (t < 64) {
            int row = tile + t;
            float v = sD[t][0] + sD[t][1] + rb[0];
            int b = (row < n) ? batch[row] : -1;
            if (row >= n) v = 0.f;
            #pragma unroll
            for (int d = 1; d < 64; d <<= 1) {
                int   ob = __shfl_up(b, d);
                float ov = __shfl_up(v, d);
                if (t >= d && ob == b) v += ov;
            }
            int nb2 = __shfl_down(b, 1);
            bool lastl = (t == 63) || (nb2 != b);
            if (lastl && b >= 0) atomicAdd(&gout[b], v);
        }
    }
}

// ---------------------------------------------------------------------------
extern "C" void kernel_launch(void* const* d_in, const int* in_sizes, int n_in,
                              void* d_out, int out_size, void* d_ws, size_t ws_size,
                              hipStream_t stream)
{
    const int N = in_sizes[0];
    const int E = in_sizes[1] / 2;
    const int G = out_size;

    const int*   x      = (const int*)d_in[0];
    const int*   ei     = (const int*)d_in[1];
    const int*   batch  = (const int*)d_in[2];
    const float* table  = (const float*)d_in[3];
    const float* bn_g   = (const float*)d_in[4];
    const float* bn_b   = (const float*)d_in[5];
    const float* bn_m   = (const float*)d_in[6];
    const float* bn_v   = (const float*)d_in[7];
    const float* lin_w  = (const float*)d_in[8];
    const float* lin_b  = (const float*)d_in[9];
    const float* epsv   = (const float*)d_in[10];
    const float* mlp_w1 = (const float*)d_in[11];
    const float* mlp_b1 = (const float*)d_in[12];
    const float* mbn_g  = (const float*)d_in[13];
    const float* mbn_b  = (const float*)d_in[14];
    const float* mbn_m  = (const float*)d_in[15];
    const float* mbn_v  = (const float*)d_in[16];
    const float* mlp_w2 = (const float*)d_in[17];
    const float* mlp_b2 = (const float*)d_in[18];
    const float* ro_w   = (const float*)d_in[19];
    const float* ro_b   = (const float*)d_in[20];

    const int* esrc_in = ei;
    const int* edst_in = ei + E;

    char* wsp = (char*)d_ws;
    size_t off = 0;
    auto alloc = [&](size_t bytes) {
        void* p = wsp + off;
        off += (bytes + 255) & ~(size_t)255;
        return p;
    };
    _Float16* bufA  = (_Float16*)alloc((size_t)N * HD * 2);  // h
    _Float16* bufB  = (_Float16*)alloc((size_t)N * HD * 2);  // h2
    _Float16* wtl   = (_Float16*)alloc((size_t)NLAYER * HD * HD * 2);
    _Float16* wt1   = (_Float16*)alloc((size_t)NLAYER * HD * HD * 2);
    _Float16* wt2   = (_Float16*)alloc((size_t)NLAYER * HD * HD * 2);
    float*    fbl   = (float*)alloc((size_t)NLAYER * HD * 4);
    float*    fb1   = (float*)alloc((size_t)NLAYER * HD * 4);
    int*      deg   = (int*)alloc((size_t)N * 4);
    int*      rowst = (int*)alloc((size_t)(N + 1) * 4);
    int*      cursor= (int*)alloc((size_t)N * 4);
    unsigned short* esrc = (unsigned short*)alloc((size_t)E * 2);
    int*      part  = (int*)alloc(256 * 4);
    (void)ws_size;

    hipMemsetAsync(deg, 0, (size_t)N * 4, stream);
    hipMemsetAsync(d_out, 0, (size_t)G * 4, stream);

    prep_weights<<<NLAYER, HD, 0, stream>>>(
        bn_g, bn_b, bn_m, bn_v, lin_w, lin_b,
        mbn_g, mbn_b, mbn_m, mbn_v, mlp_w1, mlp_b1, mlp_w2,
        wtl, fbl, wt1, fb1, wt2);

    // XCD-range-partitioned CSR build
    const int npr = (N + 7) / 8;
    const int chunks = (E + EPB - 1) / EPB;
    count_deg<<<chunks * 8, 256, 0, stream>>>(edst_in, deg, E, npr);
    int nb = (N + 1023) / 1024;
    scan_blocks<<<nb, 256, 0, stream>>>(deg, rowst, part, N);
    scan_small<<<1, 64, 0, stream>>>(part, nb);
    scan_add<<<(N + 255) / 256, 256, 0, stream>>>(rowst, cursor, part, N, E);
    fill_csr<<<chunks * 8, 256, 0, stream>>>(esrc_in, edst_in, cursor, esrc, E, npr);

    const int gemm_grid = (N + 63) / 64;

    for (int l = 0; l < NLAYER; ++l) {
        const _Float16* wl = wtl + (size_t)l * HD * HD;
        const float*    bl = fbl + (size_t)l * HD;
        const _Float16* w1 = wt1 + (size_t)l * HD * HD;
        const float*    b1 = fb1 + (size_t)l * HD;
        const _Float16* w2 = wt2 + (size_t)l * HD * HD;
        const float*    b2 = mlp_b2 + (size_t)l * HD;

        if (l == 0)
            lin_mfma<true><<<gemm_grid, 256, 0, stream>>>(
                table, nullptr, x, wl, bl, bufB, N);
        else
            lin_mfma<false><<<gemm_grid, 256, 0, stream>>>(
                nullptr, bufA, nullptr, wl, bl, bufB, N);

        if (l < NLAYER - 1)
            aggmlp<false><<<gemm_grid, 256, 0, stream>>>(
                bufB, rowst, esrc, epsv, l, w1, b1, w2, b2, bufA,
                nullptr, nullptr, nullptr, nullptr, N);
        else
            aggmlp<true><<<gemm_grid, 256, 0, stream>>>(
                bufB, rowst, esrc, epsv, l, w1, b1, w2, b2, nullptr,
                ro_w, ro_b, batch, (float*)d_out, N);
    }
}

// Round 10
// 399.488 us; speedup vs baseline: 1.1604x; 1.1604x over previous
//
#include <hip/hip_runtime.h>
#include <hip/hip_fp16.h>

// ---------------------------------------------------------------------------
// GIN forward (eval mode), fp16-MFMA version.
// prep: fold BN into weights, transpose to [n][k] f16.
// CSR build XCD-range-partitioned (dst-range bid&7), esrc u16.
// Pipeline (7 main kernels):
//   lin_mfma (embed-gather + MFMA GEMM + relu -> h2_0)
//   aggregate_f16 (wave-per-node gather-sum; max TLP — R9 lesson)
//   mlp3<false> (GEMM1+relu -> GEMM2+b2 -> GEMM3+relu = next lin; tile-local
//                triple GEMM, h never touches memory)
//   ... repeat ...
//   mlp3<true>  (GEMM1 -> GEMM2 -> fused readout + segmented-scan reduce)
// ---------------------------------------------------------------------------

#define HD 128
#define NLAYER 3
#define PITCH 136   // f16 units per LDS row (272 B = 17 x 16 B chunks)
#define EPB 2048    // edges per (chunk) block in CSR build

typedef _Float16 half8 __attribute__((ext_vector_type(8)));
typedef float    f32x4 __attribute__((ext_vector_type(4)));

// ---------------- prep: fold BN, convert + transpose weights to f16 --------
__global__ void prep_weights(
    const float* __restrict__ bn_g, const float* __restrict__ bn_b,
    const float* __restrict__ bn_m, const float* __restrict__ bn_v,
    const float* __restrict__ lin_w, const float* __restrict__ lin_b,
    const float* __restrict__ mbn_g, const float* __restrict__ mbn_b,
    const float* __restrict__ mbn_m, const float* __restrict__ mbn_v,
    const float* __restrict__ mlp_w1, const float* __restrict__ mlp_b1,
    const float* __restrict__ mlp_w2,
    _Float16* __restrict__ wtl, float* __restrict__ fbl,
    _Float16* __restrict__ wt1, float* __restrict__ fb1,
    _Float16* __restrict__ wt2)
{
    const int l = blockIdx.x;
    const int t = threadIdx.x;          // 128 threads
    __shared__ float sa[HD], sc[HD], sa2[HD];

    const int lb = l * HD;
    const int wb = l * HD * HD;
    float a  = bn_g[lb + t] * rsqrtf(bn_v[lb + t] + 1e-5f);
    float c  = bn_b[lb + t] - bn_m[lb + t] * a;
    float a2 = mbn_g[lb + t] * rsqrtf(mbn_v[lb + t] + 1e-5f);
    float c2 = mbn_b[lb + t] - mbn_m[lb + t] * a2;
    sa[t] = a; sc[t] = c; sa2[t] = a2;
    __syncthreads();

    float accb = lin_b[lb + t];
    for (int k = 0; k < HD; ++k) accb += sc[k] * lin_w[wb + k * HD + t];
    fbl[lb + t] = accb;
    fb1[lb + t] = a2 * mlp_b1[lb + t] + c2;

    // transposed f16 weights: Wt[j][k]; thread t = k, loop j -> coalesced writes
    for (int j = 0; j < HD; ++j) {
        wtl[wb + j * HD + t] = (_Float16)(sa[t] * lin_w[wb + t * HD + j]);
        wt1[wb + j * HD + t] = (_Float16)(sa2[j] * mlp_w1[wb + t * HD + j]);
        wt2[wb + j * HD + t] = (_Float16)(mlp_w2[wb + t * HD + j]);
    }
}

// ---------------- CSR build (XCD-range partitioned) ----------------
__global__ void count_deg(const int* __restrict__ dst, int* __restrict__ deg,
                          int e, int npr)
{
    int r = blockIdx.x & 7;
    int chunk = blockIdx.x >> 3;
    int lo = r * npr, hi = lo + npr;
    int base = chunk * EPB;
    int end = base + EPB; if (end > e) end = e;
    for (int i = base + threadIdx.x; i < end; i += 256) {
        int d = dst[i];
        if (d >= lo && d < hi) atomicAdd(&deg[d], 1);
    }
}

__global__ void fill_csr(const int* __restrict__ src, const int* __restrict__ dst,
                         int* __restrict__ cursor,
                         unsigned short* __restrict__ esrc, int e, int npr)
{
    int r = blockIdx.x & 7;
    int chunk = blockIdx.x >> 3;
    int lo = r * npr, hi = lo + npr;
    int base = chunk * EPB;
    int end = base + EPB; if (end > e) end = e;
    for (int i = base + threadIdx.x; i < end; i += 256) {
        int d = dst[i];
        int s = src[i];
        if (d >= lo && d < hi) {
            int p = atomicAdd(&cursor[d], 1);
            esrc[p] = (unsigned short)s;
        }
    }
}

__global__ void scan_blocks(const int* __restrict__ deg, int* __restrict__ excl,
                            int* __restrict__ partials, int n)
{
    __shared__ int wt[4];
    int t = threadIdx.x;
    int base = blockIdx.x * 1024 + t * 4;
    int v0 = (base + 0 < n) ? deg[base + 0] : 0;
    int v1 = (base + 1 < n) ? deg[base + 1] : 0;
    int v2 = (base + 2 < n) ? deg[base + 2] : 0;
    int v3 = (base + 3 < n) ? deg[base + 3] : 0;
    int s = v0 + v1 + v2 + v3;
    int lane = t & 63, w = t >> 6;
    int inc = s;
    #pragma unroll
    for (int d = 1; d < 64; d <<= 1) {
        int o = __shfl_up(inc, d);
        if (lane >= d) inc += o;
    }
    if (lane == 63) wt[w] = inc;
    __syncthreads();
    int off = 0;
    for (int i = 0; i < w; ++i) off += wt[i];
    int ex = off + inc - s;
    if (base + 0 < n) excl[base + 0] = ex; ex += v0;
    if (base + 1 < n) excl[base + 1] = ex; ex += v1;
    if (base + 2 < n) excl[base + 2] = ex; ex += v2;
    if (base + 3 < n) excl[base + 3] = ex;
    if (t == 255) partials[blockIdx.x] = off + inc;
}

__global__ void scan_small(int* __restrict__ partials, int nb)
{
    int t = threadIdx.x;
    int v = (t < nb) ? partials[t] : 0;
    int inc = v;
    #pragma unroll
    for (int d = 1; d < 64; d <<= 1) {
        int o = __shfl_up(inc, d);
        if (t >= d) inc += o;
    }
    if (t < nb) partials[t] = inc - v;
}

__global__ void scan_add(int* __restrict__ rowst, int* __restrict__ cursor,
                         const int* __restrict__ partials, int n, int e)
{
    int idx = blockIdx.x * blockDim.x + threadIdx.x;
    if (idx < n) {
        int v = rowst[idx] + partials[idx >> 10];
        rowst[idx] = v;
        cursor[idx] = v;
    }
    if (idx == 0) rowst[n] = e;
}

// ---------------- lin_mfma: H2 = relu(embed[x] @ W + B) -> f16 (layer 0) ---
__global__ __launch_bounds__(256, 3)
void lin_mfma(const float* __restrict__ Xf, const int* __restrict__ xidx,
              const _Float16* __restrict__ Wt, const float* __restrict__ B,
              _Float16* __restrict__ Y, int n)
{
    __shared__ __align__(16) _Float16 sA[64 * PITCH];
    const int t = threadIdx.x;
    const int lane = t & 63;
    const int w = t >> 6;
    const int rw_ = w >> 1, cw = w & 1;
    const int m = lane & 15, g = lane >> 4;
    const int tile = blockIdx.x * 64;

    {
        int row = t >> 2, q = t & 3;
        int gr = tile + row;
        _Float16* dst = &sA[row * PITCH + q * 32];
        if (gr < n) {
            int id = xidx[gr];
            const float4* src = reinterpret_cast<const float4*>(Xf + (size_t)id * HD) + q * 8;
            #pragma unroll
            for (int c = 0; c < 4; ++c) {
                float4 va = src[2 * c], vb = src[2 * c + 1];
                half8 h = {(_Float16)va.x, (_Float16)va.y, (_Float16)va.z, (_Float16)va.w,
                           (_Float16)vb.x, (_Float16)vb.y, (_Float16)vb.z, (_Float16)vb.w};
                *reinterpret_cast<half8*>(dst + c * 8) = h;
            }
        } else {
            half8 zz = {0, 0, 0, 0, 0, 0, 0, 0};
            #pragma unroll
            for (int c = 0; c < 4; ++c) *reinterpret_cast<half8*>(dst + c * 8) = zz;
        }
    }
    __syncthreads();

    half8 bf[4][4];
    #pragma unroll
    for (int ct4 = 0; ct4 < 4; ++ct4) {
        int ct = 4 * cw + ct4;
        #pragma unroll
        for (int kk = 0; kk < 4; ++kk)
            bf[ct4][kk] = *reinterpret_cast<const half8*>(
                Wt + (size_t)(16 * ct + m) * HD + kk * 32 + g * 8);
    }

    f32x4 acc[2][4];
    #pragma unroll
    for (int i = 0; i < 2; ++i)
        #pragma unroll
        for (int j = 0; j < 4; ++j) acc[i][j] = (f32x4){0.f, 0.f, 0.f, 0.f};

    #pragma unroll
    for (int rg2 = 0; rg2 < 2; ++rg2) {
        int rg = 2 * rw_ + rg2;
        #pragma unroll
        for (int kk = 0; kk < 4; ++kk) {
            half8 a = *reinterpret_cast<const half8*>(
                &sA[(16 * rg + m) * PITCH + kk * 32 + g * 8]);
            #pragma unroll
            for (int ct4 = 0; ct4 < 4; ++ct4)
                acc[rg2][ct4] = __builtin_amdgcn_mfma_f32_16x16x32_f16(
                    a, bf[ct4][kk], acc[rg2][ct4], 0, 0, 0);
        }
    }

    #pragma unroll
    for (int rg2 = 0; rg2 < 2; ++rg2) {
        int rg = 2 * rw_ + rg2;
        #pragma unroll
        for (int ct4 = 0; ct4 < 4; ++ct4) {
            int col = 16 * (4 * cw + ct4) + m;
            float bb = B[col];
            #pragma unroll
            for (int reg = 0; reg < 4; ++reg) {
                int r = tile + 16 * rg + 4 * g + reg;
                if (r < n) {
                    float v = fmaxf(acc[rg2][ct4][reg] + bb, 0.f);
                    Y[(size_t)r * HD + col] = (_Float16)v;
                }
            }
        }
    }
}

// ---------------- aggregate: z = (1+eps)*h2 + sum in-edge h2[src], f16 -----
// One wave per node (max TLP — this is latency-bound; R9 showed serializing
// nodes into waves costs far more than the saved traffic).
__global__ void aggregate_f16(const _Float16* __restrict__ h2,
                              const int* __restrict__ rowst,
                              const unsigned short* __restrict__ esrc,
                              const float* __restrict__ epsp,
                              int layer, _Float16* __restrict__ z, int n)
{
    int gw = (blockIdx.x * blockDim.x + threadIdx.x) >> 6;
    int lane = threadIdx.x & 63;
    if (gw >= n) return;
    float se = 1.0f + epsp[layer];
    int rs = __builtin_amdgcn_readfirstlane(rowst[gw]);
    int re = __builtin_amdgcn_readfirstlane(rowst[gw + 1]);
    const half2* hv = reinterpret_cast<const half2*>(h2);
    float2 s = __half22float2(hv[(size_t)gw * 64 + lane]);
    float ax0 = se * s.x, ay0 = se * s.y;
    float ax1 = 0.f, ay1 = 0.f, ax2 = 0.f, ay2 = 0.f, ax3 = 0.f, ay3 = 0.f;
    float ax4 = 0.f, ay4 = 0.f, ax5 = 0.f, ay5 = 0.f, ax6 = 0.f, ay6 = 0.f, ax7 = 0.f, ay7 = 0.f;
    for (int base = rs; base < re; base += 64) {
        int cnt = re - base; if (cnt > 64) cnt = 64;
        int eid = (base + lane < re) ? (int)esrc[base + lane] : 0;
        int j = 0;
        for (; j + 8 <= cnt; j += 8) {
            int s0 = __shfl(eid, j + 0);
            int s1 = __shfl(eid, j + 1);
            int s2 = __shfl(eid, j + 2);
            int s3 = __shfl(eid, j + 3);
            int s4 = __shfl(eid, j + 4);
            int s5 = __shfl(eid, j + 5);
            int s6 = __shfl(eid, j + 6);
            int s7 = __shfl(eid, j + 7);
            float2 v0 = __half22float2(hv[(size_t)s0 * 64 + lane]);
            float2 v1 = __half22float2(hv[(size_t)s1 * 64 + lane]);
            float2 v2 = __half22float2(hv[(size_t)s2 * 64 + lane]);
            float2 v3 = __half22float2(hv[(size_t)s3 * 64 + lane]);
            float2 v4 = __half22float2(hv[(size_t)s4 * 64 + lane]);
            float2 v5 = __half22float2(hv[(size_t)s5 * 64 + lane]);
            float2 v6 = __half22float2(hv[(size_t)s6 * 64 + lane]);
            float2 v7 = __half22float2(hv[(size_t)s7 * 64 + lane]);
            ax0 += v0.x; ay0 += v0.y;  ax1 += v1.x; ay1 += v1.y;
            ax2 += v2.x; ay2 += v2.y;  ax3 += v3.x; ay3 += v3.y;
            ax4 += v4.x; ay4 += v4.y;  ax5 += v5.x; ay5 += v5.y;
            ax6 += v6.x; ay6 += v6.y;  ax7 += v7.x; ay7 += v7.y;
        }
        for (; j < cnt; ++j) {
            int s0 = __shfl(eid, j);
            float2 v0 = __half22float2(hv[(size_t)s0 * 64 + lane]);
            ax0 += v0.x; ay0 += v0.y;
        }
    }
    float ox = ((ax0 + ax1) + (ax2 + ax3)) + ((ax4 + ax5) + (ax6 + ax7));
    float oy = ((ay0 + ay1) + (ay2 + ay3)) + ((ay4 + ay5) + (ay6 + ay7));
    reinterpret_cast<half2*>(z)[(size_t)gw * 64 + lane] = __floats2half2_rn(ox, oy);
}

// ---------------- mlp3: triple-GEMM ---------------------------------------
// H = relu(Z@W1+B1)@W2+B2; if !LAST additionally H2' = relu(H@W3+B3) -> Y
// (next layer's lin fused — same 64-row tile, h never hits memory).
// If LAST: readout dot + segmented-scan graph reduce.
template<bool LAST>
__global__ __launch_bounds__(256, 3)
void mlp3(const _Float16* __restrict__ Z,
          const _Float16* __restrict__ Wt1, const float* __restrict__ B1,
          const _Float16* __restrict__ Wt2, const float* __restrict__ B2,
          const _Float16* __restrict__ Wt3, const float* __restrict__ B3,
          _Float16* __restrict__ Y,
          const float* __restrict__ rw, const float* __restrict__ rb,
          const int* __restrict__ batch, float* __restrict__ gout, int n)
{
    __shared__ __align__(16) _Float16 sA[64 * PITCH];
    __shared__ float sD[64][2];
    const int t = threadIdx.x;
    const int lane = t & 63;
    const int w = t >> 6;
    const int rw_ = w >> 1, cw = w & 1;
    const int m = lane & 15, g = lane >> 4;
    const int tile = blockIdx.x * 64;

    // ---- stage Z tile ----
    {
        int row = t >> 2, q = t & 3;
        int gr = tile + row;
        _Float16* dst = &sA[row * PITCH + q * 32];
        half8 zz = {0, 0, 0, 0, 0, 0, 0, 0};
        const half8* src = reinterpret_cast<const half8*>(Z + (size_t)gr * HD + q * 32);
        #pragma unroll
        for (int c = 0; c < 4; ++c)
            *reinterpret_cast<half8*>(dst + c * 8) = (gr < n) ? src[c] : zz;
    }
    __syncthreads();

    half8 bf[4][4];
    f32x4 acc[2][4];

    // ---- GEMM1: z2 = relu(Z@W1+B1) ----
    #pragma unroll
    for (int ct4 = 0; ct4 < 4; ++ct4) {
        int ct = 4 * cw + ct4;
        #pragma unroll
        for (int kk = 0; kk < 4; ++kk)
            bf[ct4][kk] = *reinterpret_cast<const half8*>(
                Wt1 + (size_t)(16 * ct + m) * HD + kk * 32 + g * 8);
    }
    #pragma unroll
    for (int i = 0; i < 2; ++i)
        #pragma unroll
        for (int j = 0; j < 4; ++j) acc[i][j] = (f32x4){0.f, 0.f, 0.f, 0.f};
    #pragma unroll
    for (int rg2 = 0; rg2 < 2; ++rg2) {
        int rg = 2 * rw_ + rg2;
        #pragma unroll
        for (int kk = 0; kk < 4; ++kk) {
            half8 a = *reinterpret_cast<const half8*>(
                &sA[(16 * rg + m) * PITCH + kk * 32 + g * 8]);
            #pragma unroll
            for (int ct4 = 0; ct4 < 4; ++ct4)
                acc[rg2][ct4] = __builtin_amdgcn_mfma_f32_16x16x32_f16(
                    a, bf[ct4][kk], acc[rg2][ct4], 0, 0, 0);
        }
    }
    __syncthreads();
    #pragma unroll
    for (int rg2 = 0; rg2 < 2; ++rg2) {
        int rg = 2 * rw_ + rg2;
        #pragma unroll
        for (int ct4 = 0; ct4 < 4; ++ct4) {
            int col = 16 * (4 * cw + ct4) + m;
            float bb = B1[col];
            #pragma unroll
            for (int reg = 0; reg < 4; ++reg) {
                int lr = 16 * rg + 4 * g + reg;
                sA[lr * PITCH + col] = (_Float16)fmaxf(acc[rg2][ct4][reg] + bb, 0.f);
            }
        }
    }
    __syncthreads();

    // ---- GEMM2: h = z2@W2+B2 ----
    #pragma unroll
    for (int ct4 = 0; ct4 < 4; ++ct4) {
        int ct = 4 * cw + ct4;
        #pragma unroll
        for (int kk = 0; kk < 4; ++kk)
            bf[ct4][kk] = *reinterpret_cast<const half8*>(
                Wt2 + (size_t)(16 * ct + m) * HD + kk * 32 + g * 8);
    }
    f32x4 acc2[2][4];
    #pragma unroll
    for (int i = 0; i < 2; ++i)
        #pragma unroll
        for (int j = 0; j < 4; ++j) acc2[i][j] = (f32x4){0.f, 0.f, 0.f, 0.f};
    #pragma unroll
    for (int rg2 = 0; rg2 < 2; ++rg2) {
        int rg = 2 * rw_ + rg2;
        #pragma unroll
        for (int kk = 0; kk < 4; ++kk) {
            half8 a = *reinterpret_cast<const half8*>(
                &sA[(16 * rg + m) * PITCH + kk * 32 + g * 8]);
            #pragma unroll
            for (int ct4 = 0; ct4 < 4; ++ct4)
                acc2[rg2][ct4] = __builtin_amdgcn_mfma_f32_16x16x32_f16(
                    a, bf[ct4][kk], acc2[rg2][ct4], 0, 0, 0);
        }
    }

    if (LAST) {
        // ---- fused readout ----
        #pragma unroll
        for (int rg2 = 0; rg2 < 2; ++rg2) {
            int rg = 2 * rw_ + rg2;
            float pr[4] = {0.f, 0.f, 0.f, 0.f};
            #pragma unroll
            for (int ct4 = 0; ct4 < 4; ++ct4) {
                int col = 16 * (4 * cw + ct4) + m;
                float bb = B2[col], rr = rw[col];
                #pragma unroll
                for (int reg = 0; reg < 4; ++reg)
                    pr[reg] = fmaf(acc2[rg2][ct4][reg] + bb, rr, pr[reg]);
            }
            #pragma unroll
            for (int reg = 0; reg < 4; ++reg) {
                #pragma unroll
                for (int d = 1; d < 16; d <<= 1) pr[reg] += __shfl_xor(pr[reg], d);
            }
            if (m == 0) {
                #pragma unroll
                for (int reg = 0; reg < 4; ++reg)
                    sD[16 * rg + 4 * g + reg][cw] = pr[reg];
            }
        }
        __syncthreads();
        if (t < 64) {
            int row = tile + t;
            float v = sD[t][0] + sD[t][1] + rb[0];
            int b = (row < n) ? batch[row] : -1;
            if (row >= n) v = 0.f;
            #pragma unroll
            for (int d = 1; d < 64; d <<= 1) {
                int   ob = __shfl_up(b, d);
                float ov = __shfl_up(v, d);
                if (t >= d && ob == b) v += ov;
            }
            int nb2 = __shfl_down(b, 1);
            bool lastl = (t == 63) || (nb2 != b);
            if (lastl && b >= 0) atomicAdd(&gout[b], v);
        }
    } else {
        // ---- h back into sA, then GEMM3: h2' = relu(h@W3+B3) -> Y ----
        __syncthreads();   // GEMM2 A-reads complete
        #pragma unroll
        for (int rg2 = 0; rg2 < 2; ++rg2) {
            int rg = 2 * rw_ + rg2;
            #pragma unroll
            for (int ct4 = 0; ct4 < 4; ++ct4) {
                int col = 16 * (4 * cw + ct4) + m;
                float bb = B2[col];
                #pragma unroll
                for (int reg = 0; reg < 4; ++reg) {
                    int lr = 16 * rg + 4 * g + reg;
                    sA[lr * PITCH + col] = (_Float16)(acc2[rg2][ct4][reg] + bb);
                }
            }
        }
        __syncthreads();

        #pragma unroll
        for (int ct4 = 0; ct4 < 4; ++ct4) {
            int ct = 4 * cw + ct4;
            #pragma unroll
            for (int kk = 0; kk < 4; ++kk)
                bf[ct4][kk] = *reinterpret_cast<const half8*>(
                    Wt3 + (size_t)(16 * ct + m) * HD + kk * 32 + g * 8);
        }
        #pragma unroll
        for (int i = 0; i < 2; ++i)
            #pragma unroll
            for (int j = 0; j < 4; ++j) acc[i][j] = (f32x4){0.f, 0.f, 0.f, 0.f};
        #pragma unroll
        for (int rg2 = 0; rg2 < 2; ++rg2) {
            int rg = 2 * rw_ + rg2;
            #pragma unroll
            for (int kk = 0; kk < 4; ++kk) {
                half8 a = *reinterpret_cast<const half8*>(
                    &sA[(16 * rg + m) * PITCH + kk * 32 + g * 8]);
                #pragma unroll
                for (int ct4 = 0; ct4 < 4; ++ct4)
                    acc[rg2][ct4] = __builtin_amdgcn_mfma_f32_16x16x32_f16(
                        a, bf[ct4][kk], acc[rg2][ct4], 0, 0, 0);
            }
        }
        #pragma unroll
        for (int rg2 = 0; rg2 < 2; ++rg2) {
            int rg = 2 * rw_ + rg2;
            #pragma unroll
            for (int ct4 = 0; ct4 < 4; ++ct4) {
                int col = 16 * (4 * cw + ct4) + m;
                float bb = B3[col];
                #pragma unroll
                for (int reg = 0; reg < 4; ++reg) {
                    int r = tile + 16 * rg + 4 * g + reg;
                    if (r < n) {
                        float v = fmaxf(acc[rg2][ct4][reg] + bb, 0.f);
                        Y[(size_t)r * HD + col] = (_Float16)v;
                    }
                }
            }
        }
    }
}

// ---------------------------------------------------------------------------
extern "C" void kernel_launch(void* const* d_in, const int* in_sizes, int n_in,
                              void* d_out, int out_size, void* d_ws, size_t ws_size,
                              hipStream_t stream)
{
    const int N = in_sizes[0];
    const int E = in_sizes[1] / 2;
    const int G = out_size;

    const int*   x      = (const int*)d_in[0];
    const int*   ei     = (const int*)d_in[1];
    const int*   batch  = (const int*)d_in[2];
    const float* table  = (const float*)d_in[3];
    const float* bn_g   = (const float*)d_in[4];
    const float* bn_b   = (const float*)d_in[5];
    const float* bn_m   = (const float*)d_in[6];
    const float* bn_v   = (const float*)d_in[7];
    const float* lin_w  = (const float*)d_in[8];
    const float* lin_b  = (const float*)d_in[9];
    const float* epsv   = (const float*)d_in[10];
    const float* mlp_w1 = (const float*)d_in[11];
    const float* mlp_b1 = (const float*)d_in[12];
    const float* mbn_g  = (const float*)d_in[13];
    const float* mbn_b  = (const float*)d_in[14];
    const float* mbn_m  = (const float*)d_in[15];
    const float* mbn_v  = (const float*)d_in[16];
    const float* mlp_w2 = (const float*)d_in[17];
    const float* mlp_b2 = (const float*)d_in[18];
    const float* ro_w   = (const float*)d_in[19];
    const float* ro_b   = (const float*)d_in[20];

    const int* esrc_in = ei;
    const int* edst_in = ei + E;

    char* wsp = (char*)d_ws;
    size_t off = 0;
    auto alloc = [&](size_t bytes) {
        void* p = wsp + off;
        off += (bytes + 255) & ~(size_t)255;
        return p;
    };
    _Float16* bufA  = (_Float16*)alloc((size_t)N * HD * 2);  // z
    _Float16* bufB  = (_Float16*)alloc((size_t)N * HD * 2);  // h2
    _Float16* wtl   = (_Float16*)alloc((size_t)NLAYER * HD * HD * 2);
    _Float16* wt1   = (_Float16*)alloc((size_t)NLAYER * HD * HD * 2);
    _Float16* wt2   = (_Float16*)alloc((size_t)NLAYER * HD * HD * 2);
    float*    fbl   = (float*)alloc((size_t)NLAYER * HD * 4);
    float*    fb1   = (float*)alloc((size_t)NLAYER * HD * 4);
    int*      deg   = (int*)alloc((size_t)N * 4);
    int*      rowst = (int*)alloc((size_t)(N + 1) * 4);
    int*      cursor= (int*)alloc((size_t)N * 4);
    unsigned short* esrc = (unsigned short*)alloc((size_t)E * 2);
    int*      part  = (int*)alloc(1024 * 4);
    (void)ws_size;

    hipMemsetAsync(deg, 0, (size_t)N * 4, stream);
    hipMemsetAsync(d_out, 0, (size_t)G * 4, stream);

    prep_weights<<<NLAYER, HD, 0, stream>>>(
        bn_g, bn_b, bn_m, bn_v, lin_w, lin_b,
        mbn_g, mbn_b, mbn_m, mbn_v, mlp_w1, mlp_b1, mlp_w2,
        wtl, fbl, wt1, fb1, wt2);

    // XCD-range-partitioned CSR build
    const int npr = (N + 7) / 8;
    const int chunks = (E + EPB - 1) / EPB;
    count_deg<<<chunks * 8, 256, 0, stream>>>(edst_in, deg, E, npr);
    int nb = (N + 1023) / 1024;
    scan_blocks<<<nb, 256, 0, stream>>>(deg, rowst, part, N);
    scan_small<<<1, 64, 0, stream>>>(part, nb);
    scan_add<<<(N + 255) / 256, 256, 0, stream>>>(rowst, cursor, part, N, E);
    fill_csr<<<chunks * 8, 256, 0, stream>>>(esrc_in, edst_in, cursor, esrc, E, npr);

    const int gemm_grid = (N + 63) / 64;
    const int wave_grid = (N + 3) / 4;

    // layer 0 lin (embed gather)
    lin_mfma<<<gemm_grid, 256, 0, stream>>>(table, x, wtl, fbl, bufB, N);

    for (int l = 0; l < NLAYER; ++l) {
        const _Float16* w1 = wt1 + (size_t)l * HD * HD;
        const float*    b1 = fb1 + (size_t)l * HD;
        const _Float16* w2 = wt2 + (size_t)l * HD * HD;
        const float*    b2 = mlp_b2 + (size_t)l * HD;

        aggregate_f16<<<wave_grid, 256, 0, stream>>>(
            bufB, rowst, esrc, epsv, l, bufA, N);

        if (l < NLAYER - 1) {
            // mlp of layer l + lin of layer l+1, fused (tile-local)
            const _Float16* w3 = wtl + (size_t)(l + 1) * HD * HD;
            const float*    b3 = fbl + (size_t)(l + 1) * HD;
            mlp3<false><<<gemm_grid, 256, 0, stream>>>(
                bufA, w1, b1, w2, b2, w3, b3, bufB,
                nullptr, nullptr, nullptr, nullptr, N);
        } else {
            mlp3<true><<<gemm_grid, 256, 0, stream>>>(
                bufA, w1, b1, w2, b2, nullptr, nullptr, nullptr,
                ro_w, ro_b, batch, (float*)d_out, N);
        }
    }
}

// Round 11
// 390.666 us; speedup vs baseline: 1.1866x; 1.0226x over previous
//
#include <hip/hip_runtime.h>
#include <hip/hip_fp16.h>

// ---------------------------------------------------------------------------
// GIN forward (eval mode), fp16-MFMA version.
// prep: fold BN into weights, transpose to [n][k] f16.
// CSR build XCD-range-partitioned (dst-range bid&7), esrc u16.
// Pipeline:
//   lin_mfma (embed-gather + MFMA GEMM + relu -> h2_0)
//   aggregate_f16 (wave-per-node; readlane->SGPR-base gathers, 16-deep MLP)
//   mlp3<false> (GEMM1+relu -> GEMM2+b2 -> GEMM3+relu = next lin)
//   mlp3<true>  (GEMM1 -> GEMM2 -> fused readout + segmented-scan reduce)
// ---------------------------------------------------------------------------

#define HD 128
#define NLAYER 3
#define PITCH 136   // f16 units per LDS row (272 B = 17 x 16 B chunks)
#define EPB 2048    // edges per (chunk) block in CSR build

typedef _Float16 half8 __attribute__((ext_vector_type(8)));
typedef float    f32x4 __attribute__((ext_vector_type(4)));

// ---------------- prep: fold BN, convert + transpose weights to f16 --------
__global__ void prep_weights(
    const float* __restrict__ bn_g, const float* __restrict__ bn_b,
    const float* __restrict__ bn_m, const float* __restrict__ bn_v,
    const float* __restrict__ lin_w, const float* __restrict__ lin_b,
    const float* __restrict__ mbn_g, const float* __restrict__ mbn_b,
    const float* __restrict__ mbn_m, const float* __restrict__ mbn_v,
    const float* __restrict__ mlp_w1, const float* __restrict__ mlp_b1,
    const float* __restrict__ mlp_w2,
    _Float16* __restrict__ wtl, float* __restrict__ fbl,
    _Float16* __restrict__ wt1, float* __restrict__ fb1,
    _Float16* __restrict__ wt2)
{
    const int l = blockIdx.x;
    const int t = threadIdx.x;          // 128 threads
    __shared__ float sa[HD], sc[HD], sa2[HD];

    const int lb = l * HD;
    const int wb = l * HD * HD;
    float a  = bn_g[lb + t] * rsqrtf(bn_v[lb + t] + 1e-5f);
    float c  = bn_b[lb + t] - bn_m[lb + t] * a;
    float a2 = mbn_g[lb + t] * rsqrtf(mbn_v[lb + t] + 1e-5f);
    float c2 = mbn_b[lb + t] - mbn_m[lb + t] * a2;
    sa[t] = a; sc[t] = c; sa2[t] = a2;
    __syncthreads();

    float accb = lin_b[lb + t];
    for (int k = 0; k < HD; ++k) accb += sc[k] * lin_w[wb + k * HD + t];
    fbl[lb + t] = accb;
    fb1[lb + t] = a2 * mlp_b1[lb + t] + c2;

    // transposed f16 weights: Wt[j][k]; thread t = k, loop j -> coalesced writes
    for (int j = 0; j < HD; ++j) {
        wtl[wb + j * HD + t] = (_Float16)(sa[t] * lin_w[wb + t * HD + j]);
        wt1[wb + j * HD + t] = (_Float16)(sa2[j] * mlp_w1[wb + t * HD + j]);
        wt2[wb + j * HD + t] = (_Float16)(mlp_w2[wb + t * HD + j]);
    }
}

// ---------------- CSR build (XCD-range partitioned) ----------------
__global__ void count_deg(const int* __restrict__ dst, int* __restrict__ deg,
                          int e, int npr)
{
    int r = blockIdx.x & 7;
    int chunk = blockIdx.x >> 3;
    int lo = r * npr, hi = lo + npr;
    int base = chunk * EPB;
    int end = base + EPB; if (end > e) end = e;
    for (int i = base + threadIdx.x; i < end; i += 256) {
        int d = dst[i];
        if (d >= lo && d < hi) atomicAdd(&deg[d], 1);
    }
}

__global__ void fill_csr(const int* __restrict__ src, const int* __restrict__ dst,
                         int* __restrict__ cursor,
                         unsigned short* __restrict__ esrc, int e, int npr)
{
    int r = blockIdx.x & 7;
    int chunk = blockIdx.x >> 3;
    int lo = r * npr, hi = lo + npr;
    int base = chunk * EPB;
    int end = base + EPB; if (end > e) end = e;
    for (int i = base + threadIdx.x; i < end; i += 256) {
        int d = dst[i];
        int s = src[i];
        if (d >= lo && d < hi) {
            int p = atomicAdd(&cursor[d], 1);
            esrc[p] = (unsigned short)s;
        }
    }
}

__global__ void scan_blocks(const int* __restrict__ deg, int* __restrict__ excl,
                            int* __restrict__ partials, int n)
{
    __shared__ int wt[4];
    int t = threadIdx.x;
    int base = blockIdx.x * 1024 + t * 4;
    int v0 = (base + 0 < n) ? deg[base + 0] : 0;
    int v1 = (base + 1 < n) ? deg[base + 1] : 0;
    int v2 = (base + 2 < n) ? deg[base + 2] : 0;
    int v3 = (base + 3 < n) ? deg[base + 3] : 0;
    int s = v0 + v1 + v2 + v3;
    int lane = t & 63, w = t >> 6;
    int inc = s;
    #pragma unroll
    for (int d = 1; d < 64; d <<= 1) {
        int o = __shfl_up(inc, d);
        if (lane >= d) inc += o;
    }
    if (lane == 63) wt[w] = inc;
    __syncthreads();
    int off = 0;
    for (int i = 0; i < w; ++i) off += wt[i];
    int ex = off + inc - s;
    if (base + 0 < n) excl[base + 0] = ex; ex += v0;
    if (base + 1 < n) excl[base + 1] = ex; ex += v1;
    if (base + 2 < n) excl[base + 2] = ex; ex += v2;
    if (base + 3 < n) excl[base + 3] = ex;
    if (t == 255) partials[blockIdx.x] = off + inc;
}

// scan_add with inlined partials-scan (nb <= 64): every block redundantly
// scans the tiny partials array in its first wave — saves a kernel launch.
__global__ void scan_add(int* __restrict__ rowst, int* __restrict__ cursor,
                         const int* __restrict__ partials, int nb, int n, int e)
{
    __shared__ int spfx[64];
    int t = threadIdx.x;
    if (t < 64) {
        int v = (t < nb) ? partials[t] : 0;
        int inc = v;
        #pragma unroll
        for (int d = 1; d < 64; d <<= 1) {
            int o = __shfl_up(inc, d);
            if (t >= d) inc += o;
        }
        spfx[t] = inc - v;   // exclusive prefix
    }
    __syncthreads();
    int idx = blockIdx.x * blockDim.x + t;
    if (idx < n) {
        int v = rowst[idx] + spfx[idx >> 10];
        rowst[idx] = v;
        cursor[idx] = v;
    }
    if (idx == 0) rowst[n] = e;
}

// ---------------- lin_mfma: H2 = relu(embed[x] @ W + B) -> f16 (layer 0) ---
__global__ __launch_bounds__(256, 3)
void lin_mfma(const float* __restrict__ Xf, const int* __restrict__ xidx,
              const _Float16* __restrict__ Wt, const float* __restrict__ B,
              _Float16* __restrict__ Y, int n)
{
    __shared__ __align__(16) _Float16 sA[64 * PITCH];
    const int t = threadIdx.x;
    const int lane = t & 63;
    const int w = t >> 6;
    const int rw_ = w >> 1, cw = w & 1;
    const int m = lane & 15, g = lane >> 4;
    const int tile = blockIdx.x * 64;

    {
        int row = t >> 2, q = t & 3;
        int gr = tile + row;
        _Float16* dst = &sA[row * PITCH + q * 32];
        if (gr < n) {
            int id = xidx[gr];
            const float4* src = reinterpret_cast<const float4*>(Xf + (size_t)id * HD) + q * 8;
            #pragma unroll
            for (int c = 0; c < 4; ++c) {
                float4 va = src[2 * c], vb = src[2 * c + 1];
                half8 h = {(_Float16)va.x, (_Float16)va.y, (_Float16)va.z, (_Float16)va.w,
                           (_Float16)vb.x, (_Float16)vb.y, (_Float16)vb.z, (_Float16)vb.w};
                *reinterpret_cast<half8*>(dst + c * 8) = h;
            }
        } else {
            half8 zz = {0, 0, 0, 0, 0, 0, 0, 0};
            #pragma unroll
            for (int c = 0; c < 4; ++c) *reinterpret_cast<half8*>(dst + c * 8) = zz;
        }
    }
    __syncthreads();

    half8 bf[4][4];
    #pragma unroll
    for (int ct4 = 0; ct4 < 4; ++ct4) {
        int ct = 4 * cw + ct4;
        #pragma unroll
        for (int kk = 0; kk < 4; ++kk)
            bf[ct4][kk] = *reinterpret_cast<const half8*>(
                Wt + (size_t)(16 * ct + m) * HD + kk * 32 + g * 8);
    }

    f32x4 acc[2][4];
    #pragma unroll
    for (int i = 0; i < 2; ++i)
        #pragma unroll
        for (int j = 0; j < 4; ++j) acc[i][j] = (f32x4){0.f, 0.f, 0.f, 0.f};

    #pragma unroll
    for (int rg2 = 0; rg2 < 2; ++rg2) {
        int rg = 2 * rw_ + rg2;
        #pragma unroll
        for (int kk = 0; kk < 4; ++kk) {
            half8 a = *reinterpret_cast<const half8*>(
                &sA[(16 * rg + m) * PITCH + kk * 32 + g * 8]);
            #pragma unroll
            for (int ct4 = 0; ct4 < 4; ++ct4)
                acc[rg2][ct4] = __builtin_amdgcn_mfma_f32_16x16x32_f16(
                    a, bf[ct4][kk], acc[rg2][ct4], 0, 0, 0);
        }
    }

    #pragma unroll
    for (int rg2 = 0; rg2 < 2; ++rg2) {
        int rg = 2 * rw_ + rg2;
        #pragma unroll
        for (int ct4 = 0; ct4 < 4; ++ct4) {
            int col = 16 * (4 * cw + ct4) + m;
            float bb = B[col];
            #pragma unroll
            for (int reg = 0; reg < 4; ++reg) {
                int r = tile + 16 * rg + 4 * g + reg;
                if (r < n) {
                    float v = fmaxf(acc[rg2][ct4][reg] + bb, 0.f);
                    Y[(size_t)r * HD + col] = (_Float16)v;
                }
            }
        }
    }
}

// ---------------- aggregate: z = (1+eps)*h2 + sum in-edge h2[src], f16 -----
// One wave per node. Edge ids pulled to SGPR via readlane -> gather issues as
// global_load_dword v, v_laneoff, s[rowbase] (no VALU/LDS in address chain).
// 16 gathers in flight; tail via predicated 16-wide batch (clamped readlane,
// masked accumulate — duplicate loads are L1 hits).
__global__ void aggregate_f16(const _Float16* __restrict__ h2,
                              const int* __restrict__ rowst,
                              const unsigned short* __restrict__ esrc,
                              const float* __restrict__ epsp,
                              int layer, _Float16* __restrict__ z, int n)
{
    int gw = (blockIdx.x * blockDim.x + threadIdx.x) >> 6;
    int lane = threadIdx.x & 63;
    if (gw >= n) return;
    float se = 1.0f + epsp[layer];
    int rs = __builtin_amdgcn_readfirstlane(rowst[gw]);
    int re = __builtin_amdgcn_readfirstlane(rowst[gw + 1]);
    const half2* hv = reinterpret_cast<const half2*>(h2);

    float2 own = __half22float2(hv[(size_t)gw * 64 + lane]);
    float ax[8], ay[8];
    ax[0] = se * own.x; ay[0] = se * own.y;
    #pragma unroll
    for (int k = 1; k < 8; ++k) { ax[k] = 0.f; ay[k] = 0.f; }

    for (int base = rs; base < re; base += 64) {
        int cnt = re - base; if (cnt > 64) cnt = 64;
        int eid = (base + lane < re) ? (int)esrc[base + lane] : 0;
        for (int j = 0; j < cnt; j += 16) {
            half2 t[16];
            #pragma unroll
            for (int k = 0; k < 16; ++k) {
                int idx = j + k; if (idx > cnt - 1) idx = cnt - 1;   // uniform clamp
                int sid = __builtin_amdgcn_readfirstlane(
                              __builtin_amdgcn_readlane(eid, idx));
                t[k] = hv[(size_t)sid * 64 + lane];                 // SGPR-base gather
            }
            #pragma unroll
            for (int k = 0; k < 16; ++k) {
                if (j + k < cnt) {                                   // uniform predicate
                    float2 v = __half22float2(t[k]);
                    ax[k & 7] += v.x; ay[k & 7] += v.y;
                }
            }
        }
    }
    float ox = ((ax[0] + ax[1]) + (ax[2] + ax[3])) + ((ax[4] + ax[5]) + (ax[6] + ax[7]));
    float oy = ((ay[0] + ay[1]) + (ay[2] + ay[3])) + ((ay[4] + ay[5]) + (ay[6] + ay[7]));
    reinterpret_cast<half2*>(z)[(size_t)gw * 64 + lane] = __floats2half2_rn(ox, oy);
}

// ---------------- mlp3: triple-GEMM ---------------------------------------
// H = relu(Z@W1+B1)@W2+B2; if !LAST additionally H2' = relu(H@W3+B3) -> Y
// (next layer's lin fused — same 64-row tile, h never hits memory).
// If LAST: readout dot + segmented-scan graph reduce.
template<bool LAST>
__global__ __launch_bounds__(256, 3)
void mlp3(const _Float16* __restrict__ Z,
          const _Float16* __restrict__ Wt1, const float* __restrict__ B1,
          const _Float16* __restrict__ Wt2, const float* __restrict__ B2,
          const _Float16* __restrict__ Wt3, const float* __restrict__ B3,
          _Float16* __restrict__ Y,
          const float* __restrict__ rw, const float* __restrict__ rb,
          const int* __restrict__ batch, float* __restrict__ gout, int n)
{
    __shared__ __align__(16) _Float16 sA[64 * PITCH];
    __shared__ float sD[64][2];
    const int t = threadIdx.x;
    const int lane = t & 63;
    const int w = t >> 6;
    const int rw_ = w >> 1, cw = w & 1;
    const int m = lane & 15, g = lane >> 4;
    const int tile = blockIdx.x * 64;

    // ---- stage Z tile ----
    {
        int row = t >> 2, q = t & 3;
        int gr = tile + row;
        _Float16* dst = &sA[row * PITCH + q * 32];
        half8 zz = {0, 0, 0, 0, 0, 0, 0, 0};
        const half8* src = reinterpret_cast<const half8*>(Z + (size_t)gr * HD + q * 32);
        #pragma unroll
        for (int c = 0; c < 4; ++c)
            *reinterpret_cast<half8*>(dst + c * 8) = (gr < n) ? src[c] : zz;
    }
    __syncthreads();

    half8 bf[4][4];
    f32x4 acc[2][4];

    // ---- GEMM1: z2 = relu(Z@W1+B1) ----
    #pragma unroll
    for (int ct4 = 0; ct4 < 4; ++ct4) {
        int ct = 4 * cw + ct4;
        #pragma unroll
        for (int kk = 0; kk < 4; ++kk)
            bf[ct4][kk] = *reinterpret_cast<const half8*>(
                Wt1 + (size_t)(16 * ct + m) * HD + kk * 32 + g * 8);
    }
    #pragma unroll
    for (int i = 0; i < 2; ++i)
        #pragma unroll
        for (int j = 0; j < 4; ++j) acc[i][j] = (f32x4){0.f, 0.f, 0.f, 0.f};
    #pragma unroll
    for (int rg2 = 0; rg2 < 2; ++rg2) {
        int rg = 2 * rw_ + rg2;
        #pragma unroll
        for (int kk = 0; kk < 4; ++kk) {
            half8 a = *reinterpret_cast<const half8*>(
                &sA[(16 * rg + m) * PITCH + kk * 32 + g * 8]);
            #pragma unroll
            for (int ct4 = 0; ct4 < 4; ++ct4)
                acc[rg2][ct4] = __builtin_amdgcn_mfma_f32_16x16x32_f16(
                    a, bf[ct4][kk], acc[rg2][ct4], 0, 0, 0);
        }
    }
    __syncthreads();
    #pragma unroll
    for (int rg2 = 0; rg2 < 2; ++rg2) {
        int rg = 2 * rw_ + rg2;
        #pragma unroll
        for (int ct4 = 0; ct4 < 4; ++ct4) {
            int col = 16 * (4 * cw + ct4) + m;
            float bb = B1[col];
            #pragma unroll
            for (int reg = 0; reg < 4; ++reg) {
                int lr = 16 * rg + 4 * g + reg;
                sA[lr * PITCH + col] = (_Float16)fmaxf(acc[rg2][ct4][reg] + bb, 0.f);
            }
        }
    }
    __syncthreads();

    // ---- GEMM2: h = z2@W2+B2 ----
    #pragma unroll
    for (int ct4 = 0; ct4 < 4; ++ct4) {
        int ct = 4 * cw + ct4;
        #pragma unroll
        for (int kk = 0; kk < 4; ++kk)
            bf[ct4][kk] = *reinterpret_cast<const half8*>(
                Wt2 + (size_t)(16 * ct + m) * HD + kk * 32 + g * 8);
    }
    f32x4 acc2[2][4];
    #pragma unroll
    for (int i = 0; i < 2; ++i)
        #pragma unroll
        for (int j = 0; j < 4; ++j) acc2[i][j] = (f32x4){0.f, 0.f, 0.f, 0.f};
    #pragma unroll
    for (int rg2 = 0; rg2 < 2; ++rg2) {
        int rg = 2 * rw_ + rg2;
        #pragma unroll
        for (int kk = 0; kk < 4; ++kk) {
            half8 a = *reinterpret_cast<const half8*>(
                &sA[(16 * rg + m) * PITCH + kk * 32 + g * 8]);
            #pragma unroll
            for (int ct4 = 0; ct4 < 4; ++ct4)
                acc2[rg2][ct4] = __builtin_amdgcn_mfma_f32_16x16x32_f16(
                    a, bf[ct4][kk], acc2[rg2][ct4], 0, 0, 0);
        }
    }

    if (LAST) {
        // ---- fused readout ----
        #pragma unroll
        for (int rg2 = 0; rg2 < 2; ++rg2) {
            int rg = 2 * rw_ + rg2;
            float pr[4] = {0.f, 0.f, 0.f, 0.f};
            #pragma unroll
            for (int ct4 = 0; ct4 < 4; ++ct4) {
                int col = 16 * (4 * cw + ct4) + m;
                float bb = B2[col], rr = rw[col];
                #pragma unroll
                for (int reg = 0; reg < 4; ++reg)
                    pr[reg] = fmaf(acc2[rg2][ct4][reg] + bb, rr, pr[reg]);
            }
            #pragma unroll
            for (int reg = 0; reg < 4; ++reg) {
                #pragma unroll
                for (int d = 1; d < 16; d <<= 1) pr[reg] += __shfl_xor(pr[reg], d);
            }
            if (m == 0) {
                #pragma unroll
                for (int reg = 0; reg < 4; ++reg)
                    sD[16 * rg + 4 * g + reg][cw] = pr[reg];
            }
        }
        __syncthreads();
        if (t < 64) {
            int row = tile + t;
            float v = sD[t][0] + sD[t][1] + rb[0];
            int b = (row < n) ? batch[row] : -1;
            if (row >= n) v = 0.f;
            #pragma unroll
            for (int d = 1; d < 64; d <<= 1) {
                int   ob = __shfl_up(b, d);
                float ov = __shfl_up(v, d);
                if (t >= d && ob == b) v += ov;
            }
            int nb2 = __shfl_down(b, 1);
            bool lastl = (t == 63) || (nb2 != b);
            if (lastl && b >= 0) atomicAdd(&gout[b], v);
        }
    } else {
        // ---- h back into sA, then GEMM3: h2' = relu(h@W3+B3) -> Y ----
        __syncthreads();   // GEMM2 A-reads complete
        #pragma unroll
        for (int rg2 = 0; rg2 < 2; ++rg2) {
            int rg = 2 * rw_ + rg2;
            #pragma unroll
            for (int ct4 = 0; ct4 < 4; ++ct4) {
                int col = 16 * (4 * cw + ct4) + m;
                float bb = B2[col];
                #pragma unroll
                for (int reg = 0; reg < 4; ++reg) {
                    int lr = 16 * rg + 4 * g + reg;
                    sA[lr * PITCH + col] = (_Float16)(acc2[rg2][ct4][reg] + bb);
                }
            }
        }
        __syncthreads();

        #pragma unroll
        for (int ct4 = 0; ct4 < 4; ++ct4) {
            int ct = 4 * cw + ct4;
            #pragma unroll
            for (int kk = 0; kk < 4; ++kk)
                bf[ct4][kk] = *reinterpret_cast<const half8*>(
                    Wt3 + (size_t)(16 * ct + m) * HD + kk * 32 + g * 8);
        }
        #pragma unroll
        for (int i = 0; i < 2; ++i)
            #pragma unroll
            for (int j = 0; j < 4; ++j) acc[i][j] = (f32x4){0.f, 0.f, 0.f, 0.f};
        #pragma unroll
        for (int rg2 = 0; rg2 < 2; ++rg2) {
            int rg = 2 * rw_ + rg2;
            #pragma unroll
            for (int kk = 0; kk < 4; ++kk) {
                half8 a = *reinterpret_cast<const half8*>(
                    &sA[(16 * rg + m) * PITCH + kk * 32 + g * 8]);
                #pragma unroll
                for (int ct4 = 0; ct4 < 4; ++ct4)
                    acc[rg2][ct4] = __builtin_amdgcn_mfma_f32_16x16x32_f16(
                        a, bf[ct4][kk], acc[rg2][ct4], 0, 0, 0);
            }
        }
        #pragma unroll
        for (int rg2 = 0; rg2 < 2; ++rg2) {
            int rg = 2 * rw_ + rg2;
            #pragma unroll
            for (int ct4 = 0; ct4 < 4; ++ct4) {
                int col = 16 * (4 * cw + ct4) + m;
                float bb = B3[col];
                #pragma unroll
                for (int reg = 0; reg < 4; ++reg) {
                    int r = tile + 16 * rg + 4 * g + reg;
                    if (r < n) {
                        float v = fmaxf(acc[rg2][ct4][reg] + bb, 0.f);
                        Y[(size_t)r * HD + col] = (_Float16)v;
                    }
                }
            }
        }
    }
}

// ---------------------------------------------------------------------------
extern "C" void kernel_launch(void* const* d_in, const int* in_sizes, int n_in,
                              void* d_out, int out_size, void* d_ws, size_t ws_size,
                              hipStream_t stream)
{
    const int N = in_sizes[0];
    const int E = in_sizes[1] / 2;
    const int G = out_size;

    const int*   x      = (const int*)d_in[0];
    const int*   ei     = (const int*)d_in[1];
    const int*   batch  = (const int*)d_in[2];
    const float* table  = (const float*)d_in[3];
    const float* bn_g   = (const float*)d_in[4];
    const float* bn_b   = (const float*)d_in[5];
    const float* bn_m   = (const float*)d_in[6];
    const float* bn_v   = (const float*)d_in[7];
    const float* lin_w  = (const float*)d_in[8];
    const float* lin_b  = (const float*)d_in[9];
    const float* epsv   = (const float*)d_in[10];
    const float* mlp_w1 = (const float*)d_in[11];
    const float* mlp_b1 = (const float*)d_in[12];
    const float* mbn_g  = (const float*)d_in[13];
    const float* mbn_b  = (const float*)d_in[14];
    const float* mbn_m  = (const float*)d_in[15];
    const float* mbn_v  = (const float*)d_in[16];
    const float* mlp_w2 = (const float*)d_in[17];
    const float* mlp_b2 = (const float*)d_in[18];
    const float* ro_w   = (const float*)d_in[19];
    const float* ro_b   = (const float*)d_in[20];

    const int* esrc_in = ei;
    const int* edst_in = ei + E;

    char* wsp = (char*)d_ws;
    size_t off = 0;
    auto alloc = [&](size_t bytes) {
        void* p = wsp + off;
        off += (bytes + 255) & ~(size_t)255;
        return p;
    };
    _Float16* bufA  = (_Float16*)alloc((size_t)N * HD * 2);  // z
    _Float16* bufB  = (_Float16*)alloc((size_t)N * HD * 2);  // h2
    _Float16* wtl   = (_Float16*)alloc((size_t)NLAYER * HD * HD * 2);
    _Float16* wt1   = (_Float16*)alloc((size_t)NLAYER * HD * HD * 2);
    _Float16* wt2   = (_Float16*)alloc((size_t)NLAYER * HD * HD * 2);
    float*    fbl   = (float*)alloc((size_t)NLAYER * HD * 4);
    float*    fb1   = (float*)alloc((size_t)NLAYER * HD * 4);
    int*      deg   = (int*)alloc((size_t)N * 4);
    int*      rowst = (int*)alloc((size_t)(N + 1) * 4);
    int*      cursor= (int*)alloc((size_t)N * 4);
    unsigned short* esrc = (unsigned short*)alloc((size_t)E * 2);
    int*      part  = (int*)alloc(1024 * 4);
    (void)ws_size;

    hipMemsetAsync(deg, 0, (size_t)N * 4, stream);
    hipMemsetAsync(d_out, 0, (size_t)G * 4, stream);

    prep_weights<<<NLAYER, HD, 0, stream>>>(
        bn_g, bn_b, bn_m, bn_v, lin_w, lin_b,
        mbn_g, mbn_b, mbn_m, mbn_v, mlp_w1, mlp_b1, mlp_w2,
        wtl, fbl, wt1, fb1, wt2);

    // XCD-range-partitioned CSR build
    const int npr = (N + 7) / 8;
    const int chunks = (E + EPB - 1) / EPB;
    count_deg<<<chunks * 8, 256, 0, stream>>>(edst_in, deg, E, npr);
    int nb = (N + 1023) / 1024;
    scan_blocks<<<nb, 256, 0, stream>>>(deg, rowst, part, N);
    scan_add<<<(N + 255) / 256, 256, 0, stream>>>(rowst, cursor, part, nb, N, E);
    fill_csr<<<chunks * 8, 256, 0, stream>>>(esrc_in, edst_in, cursor, esrc, E, npr);

    const int gemm_grid = (N + 63) / 64;
    const int wave_grid = (N + 3) / 4;

    // layer 0 lin (embed gather)
    lin_mfma<<<gemm_grid, 256, 0, stream>>>(table, x, wtl, fbl, bufB, N);

    for (int l = 0; l < NLAYER; ++l) {
        const _Float16* w1 = wt1 + (size_t)l * HD * HD;
        const float*    b1 = fb1 + (size_t)l * HD;
        const _Float16* w2 = wt2 + (size_t)l * HD * HD;
        const float*    b2 = mlp_b2 + (size_t)l * HD;

        aggregate_f16<<<wave_grid, 256, 0, stream>>>(
            bufB, rowst, esrc, epsv, l, bufA, N);

        if (l < NLAYER - 1) {
            // mlp of layer l + lin of layer l+1, fused (tile-local)
            const _Float16* w3 = wtl + (size_t)(l + 1) * HD * HD;
            const float*    b3 = fbl + (size_t)(l + 1) * HD;
            mlp3<false><<<gemm_grid, 256, 0, stream>>>(
                bufA, w1, b1, w2, b2, w3, b3, bufB,
                nullptr, nullptr, nullptr, nullptr, N);
        } else {
            mlp3<true><<<gemm_grid, 256, 0, stream>>>(
                bufA, w1, b1, w2, b2, nullptr, nullptr, nullptr,
                ro_w, ro_b, batch, (float*)d_out, N);
        }
    }
}

// Round 12
// 380.071 us; speedup vs baseline: 1.2197x; 1.0279x over previous
//
#include <hip/hip_runtime.h>
#include <hip/hip_fp16.h>

// ---------------------------------------------------------------------------
// GIN forward (eval mode), fp16-MFMA version.
// prep fused into count_deg launch (independent front-of-pipe work).
// CSR build XCD-range-partitioned (dst-range), esrc u16.
// Pipeline:
//   prep_and_count -> scan_blocks -> scan_add -> fill_csr
//   lin_mfma (embed-gather + MFMA GEMM + relu -> h2_0)
//   per layer: aggregate_f16 (wave-per-node, readlane SGPR-base gathers)
//              mlp3 (128-row tile, 8 waves: GEMM1+relu -> GEMM2+b2 ->
//                    GEMM3+relu = next lin | last: fused readout)
// ---------------------------------------------------------------------------

#define HD 128
#define NLAYER 3
#define PITCH 136   // f16 units per LDS row (272 B)
#define EPB 2048    // edges per (chunk) block in CSR build

typedef _Float16 half8 __attribute__((ext_vector_type(8)));
typedef float    f32x4 __attribute__((ext_vector_type(4)));

// ---------------- prep (blocks 0..NLAYER-1) + count_deg (rest) -------------
__global__ void prep_and_count(
    const float* __restrict__ bn_g, const float* __restrict__ bn_b,
    const float* __restrict__ bn_m, const float* __restrict__ bn_v,
    const float* __restrict__ lin_w, const float* __restrict__ lin_b,
    const float* __restrict__ mbn_g, const float* __restrict__ mbn_b,
    const float* __restrict__ mbn_m, const float* __restrict__ mbn_v,
    const float* __restrict__ mlp_w1, const float* __restrict__ mlp_b1,
    const float* __restrict__ mlp_w2,
    _Float16* __restrict__ wtl, float* __restrict__ fbl,
    _Float16* __restrict__ wt1, float* __restrict__ fb1,
    _Float16* __restrict__ wt2,
    const int* __restrict__ dst, int* __restrict__ deg, int e, int npr)
{
    __shared__ float sa[HD], sc[HD], sa2[HD];
    const int t = threadIdx.x;

    if (blockIdx.x < NLAYER) {
        const int l = blockIdx.x;
        const int lb = l * HD;
        const int wb = l * HD * HD;
        if (t < HD) {
            float a  = bn_g[lb + t] * rsqrtf(bn_v[lb + t] + 1e-5f);
            float c  = bn_b[lb + t] - bn_m[lb + t] * a;
            float a2 = mbn_g[lb + t] * rsqrtf(mbn_v[lb + t] + 1e-5f);
            sa[t] = a; sc[t] = c; sa2[t] = a2;
        }
        __syncthreads();
        if (t < HD) {
            float a2 = sa2[t];
            float c2 = mbn_b[lb + t] - mbn_m[lb + t] * a2;

            float accb = lin_b[lb + t];
            for (int k = 0; k < HD; ++k) accb += sc[k] * lin_w[wb + k * HD + t];
            fbl[lb + t] = accb;
            fb1[lb + t] = a2 * mlp_b1[lb + t] + c2;

            for (int j = 0; j < HD; ++j) {
                wtl[wb + j * HD + t] = (_Float16)(sa[t] * lin_w[wb + t * HD + j]);
                wt1[wb + j * HD + t] = (_Float16)(sa2[j] * mlp_w1[wb + t * HD + j]);
                wt2[wb + j * HD + t] = (_Float16)(mlp_w2[wb + t * HD + j]);
            }
        }
    } else {
        int bid = blockIdx.x - NLAYER;
        int r = bid & 7;
        int chunk = bid >> 3;
        int lo = r * npr, hi = lo + npr;
        int base = chunk * EPB;
        int end = base + EPB; if (end > e) end = e;
        for (int i = base + t; i < end; i += 256) {
            int d = dst[i];
            if (d >= lo && d < hi) atomicAdd(&deg[d], 1);
        }
    }
}

__global__ void fill_csr(const int* __restrict__ src, const int* __restrict__ dst,
                         int* __restrict__ cursor,
                         unsigned short* __restrict__ esrc, int e, int npr)
{
    int r = blockIdx.x & 7;
    int chunk = blockIdx.x >> 3;
    int lo = r * npr, hi = lo + npr;
    int base = chunk * EPB;
    int end = base + EPB; if (end > e) end = e;
    for (int i = base + threadIdx.x; i < end; i += 256) {
        int d = dst[i];
        int s = src[i];
        if (d >= lo && d < hi) {
            int p = atomicAdd(&cursor[d], 1);
            esrc[p] = (unsigned short)s;
        }
    }
}

__global__ void scan_blocks(const int* __restrict__ deg, int* __restrict__ excl,
                            int* __restrict__ partials, int n)
{
    __shared__ int wt[4];
    int t = threadIdx.x;
    int base = blockIdx.x * 1024 + t * 4;
    int v0 = (base + 0 < n) ? deg[base + 0] : 0;
    int v1 = (base + 1 < n) ? deg[base + 1] : 0;
    int v2 = (base + 2 < n) ? deg[base + 2] : 0;
    int v3 = (base + 3 < n) ? deg[base + 3] : 0;
    int s = v0 + v1 + v2 + v3;
    int lane = t & 63, w = t >> 6;
    int inc = s;
    #pragma unroll
    for (int d = 1; d < 64; d <<= 1) {
        int o = __shfl_up(inc, d);
        if (lane >= d) inc += o;
    }
    if (lane == 63) wt[w] = inc;
    __syncthreads();
    int off = 0;
    for (int i = 0; i < w; ++i) off += wt[i];
    int ex = off + inc - s;
    if (base + 0 < n) excl[base + 0] = ex; ex += v0;
    if (base + 1 < n) excl[base + 1] = ex; ex += v1;
    if (base + 2 < n) excl[base + 2] = ex; ex += v2;
    if (base + 3 < n) excl[base + 3] = ex;
    if (t == 255) partials[blockIdx.x] = off + inc;
}

// scan_add with inlined partials-scan (nb <= 64)
__global__ void scan_add(int* __restrict__ rowst, int* __restrict__ cursor,
                         const int* __restrict__ partials, int nb, int n, int e)
{
    __shared__ int spfx[64];
    int t = threadIdx.x;
    if (t < 64) {
        int v = (t < nb) ? partials[t] : 0;
        int inc = v;
        #pragma unroll
        for (int d = 1; d < 64; d <<= 1) {
            int o = __shfl_up(inc, d);
            if (t >= d) inc += o;
        }
        spfx[t] = inc - v;
    }
    __syncthreads();
    int idx = blockIdx.x * blockDim.x + t;
    if (idx < n) {
        int v = rowst[idx] + spfx[idx >> 10];
        rowst[idx] = v;
        cursor[idx] = v;
    }
    if (idx == 0) rowst[n] = e;
}

// ---------------- lin_mfma: H2 = relu(embed[x] @ W + B) -> f16 (layer 0) ---
__global__ __launch_bounds__(256, 3)
void lin_mfma(const float* __restrict__ Xf, const int* __restrict__ xidx,
              const _Float16* __restrict__ Wt, const float* __restrict__ B,
              _Float16* __restrict__ Y, int n)
{
    __shared__ __align__(16) _Float16 sA[64 * PITCH];
    const int t = threadIdx.x;
    const int lane = t & 63;
    const int w = t >> 6;
    const int rw_ = w >> 1, cw = w & 1;
    const int m = lane & 15, g = lane >> 4;
    const int tile = blockIdx.x * 64;

    {
        int row = t >> 2, q = t & 3;
        int gr = tile + row;
        _Float16* dst = &sA[row * PITCH + q * 32];
        if (gr < n) {
            int id = xidx[gr];
            const float4* src = reinterpret_cast<const float4*>(Xf + (size_t)id * HD) + q * 8;
            #pragma unroll
            for (int c = 0; c < 4; ++c) {
                float4 va = src[2 * c], vb = src[2 * c + 1];
                half8 h = {(_Float16)va.x, (_Float16)va.y, (_Float16)va.z, (_Float16)va.w,
                           (_Float16)vb.x, (_Float16)vb.y, (_Float16)vb.z, (_Float16)vb.w};
                *reinterpret_cast<half8*>(dst + c * 8) = h;
            }
        } else {
            half8 zz = {0, 0, 0, 0, 0, 0, 0, 0};
            #pragma unroll
            for (int c = 0; c < 4; ++c) *reinterpret_cast<half8*>(dst + c * 8) = zz;
        }
    }
    __syncthreads();

    half8 bf[4][4];
    #pragma unroll
    for (int ct4 = 0; ct4 < 4; ++ct4) {
        int ct = 4 * cw + ct4;
        #pragma unroll
        for (int kk = 0; kk < 4; ++kk)
            bf[ct4][kk] = *reinterpret_cast<const half8*>(
                Wt + (size_t)(16 * ct + m) * HD + kk * 32 + g * 8);
    }

    f32x4 acc[2][4];
    #pragma unroll
    for (int i = 0; i < 2; ++i)
        #pragma unroll
        for (int j = 0; j < 4; ++j) acc[i][j] = (f32x4){0.f, 0.f, 0.f, 0.f};

    #pragma unroll
    for (int rg2 = 0; rg2 < 2; ++rg2) {
        int rg = 2 * rw_ + rg2;
        #pragma unroll
        for (int kk = 0; kk < 4; ++kk) {
            half8 a = *reinterpret_cast<const half8*>(
                &sA[(16 * rg + m) * PITCH + kk * 32 + g * 8]);
            #pragma unroll
            for (int ct4 = 0; ct4 < 4; ++ct4)
                acc[rg2][ct4] = __builtin_amdgcn_mfma_f32_16x16x32_f16(
                    a, bf[ct4][kk], acc[rg2][ct4], 0, 0, 0);
        }
    }

    #pragma unroll
    for (int rg2 = 0; rg2 < 2; ++rg2) {
        int rg = 2 * rw_ + rg2;
        #pragma unroll
        for (int ct4 = 0; ct4 < 4; ++ct4) {
            int col = 16 * (4 * cw + ct4) + m;
            float bb = B[col];
            #pragma unroll
            for (int reg = 0; reg < 4; ++reg) {
                int r = tile + 16 * rg + 4 * g + reg;
                if (r < n) {
                    float v = fmaxf(acc[rg2][ct4][reg] + bb, 0.f);
                    Y[(size_t)r * HD + col] = (_Float16)v;
                }
            }
        }
    }
}

// ---------------- aggregate: z = (1+eps)*h2 + sum in-edge h2[src], f16 -----
__global__ void aggregate_f16(const _Float16* __restrict__ h2,
                              const int* __restrict__ rowst,
                              const unsigned short* __restrict__ esrc,
                              const float* __restrict__ epsp,
                              int layer, _Float16* __restrict__ z, int n)
{
    int gw = (blockIdx.x * blockDim.x + threadIdx.x) >> 6;
    int lane = threadIdx.x & 63;
    if (gw >= n) return;
    float se = 1.0f + epsp[layer];
    int rs = __builtin_amdgcn_readfirstlane(rowst[gw]);
    int re = __builtin_amdgcn_readfirstlane(rowst[gw + 1]);
    const half2* hv = reinterpret_cast<const half2*>(h2);

    float2 own = __half22float2(hv[(size_t)gw * 64 + lane]);
    float ax[8], ay[8];
    ax[0] = se * own.x; ay[0] = se * own.y;
    #pragma unroll
    for (int k = 1; k < 8; ++k) { ax[k] = 0.f; ay[k] = 0.f; }

    for (int base = rs; base < re; base += 64) {
        int cnt = re - base; if (cnt > 64) cnt = 64;
        int eid = (base + lane < re) ? (int)esrc[base + lane] : 0;
        for (int j = 0; j < cnt; j += 16) {
            half2 t[16];
            #pragma unroll
            for (int k = 0; k < 16; ++k) {
                int idx = j + k; if (idx > cnt - 1) idx = cnt - 1;
                int sid = __builtin_amdgcn_readfirstlane(
                              __builtin_amdgcn_readlane(eid, idx));
                t[k] = hv[(size_t)sid * 64 + lane];
            }
            #pragma unroll
            for (int k = 0; k < 16; ++k) {
                if (j + k < cnt) {
                    float2 v = __half22float2(t[k]);
                    ax[k & 7] += v.x; ay[k & 7] += v.y;
                }
            }
        }
    }
    float ox = ((ax[0] + ax[1]) + (ax[2] + ax[3])) + ((ax[4] + ax[5]) + (ax[6] + ax[7]));
    float oy = ((ay[0] + ay[1]) + (ay[2] + ay[3])) + ((ay[4] + ay[5]) + (ay[6] + ay[7]));
    reinterpret_cast<half2*>(z)[(size_t)gw * 64 + lane] = __floats2half2_rn(ox, oy);
}

// ---------------- mlp3: triple-GEMM, 128-row tile, 8 waves -----------------
// Wave w: rows [32*(w>>1), +32), cols [64*(w&1), +64).  2 blocks/CU ->
// 16 waves/CU (vs 12 at the 64-row tile) to hide the serialized GEMM chain.
template<bool LAST>
__global__ __launch_bounds__(512)
void mlp3(const _Float16* __restrict__ Z,
          const _Float16* __restrict__ Wt1, const float* __restrict__ B1,
          const _Float16* __restrict__ Wt2, const float* __restrict__ B2,
          const _Float16* __restrict__ Wt3, const float* __restrict__ B3,
          _Float16* __restrict__ Y,
          const float* __restrict__ rw, const float* __restrict__ rb,
          const int* __restrict__ batch, float* __restrict__ gout, int n)
{
    __shared__ __align__(16) _Float16 sA[128 * PITCH];
    __shared__ float sD[128][2];
    const int t = threadIdx.x;            // 0..511
    const int lane = t & 63;
    const int w = t >> 6;                 // 0..7
    const int rw_ = w >> 1, cw = w & 1;   // 4 row-groups x 2 col-halves
    const int m = lane & 15, g = lane >> 4;
    const int tile = blockIdx.x * 128;

    // ---- stage Z tile: 128 rows x 4 quarters = 512 tasks, 1/thread ----
    {
        int row = t >> 2, q = t & 3;
        int gr = tile + row;
        _Float16* dst = &sA[row * PITCH + q * 32];
        half8 zz = {0, 0, 0, 0, 0, 0, 0, 0};
        const half8* src = reinterpret_cast<const half8*>(Z + (size_t)gr * HD + q * 32);
        #pragma unroll
        for (int c = 0; c < 4; ++c)
            *reinterpret_cast<half8*>(dst + c * 8) = (gr < n) ? src[c] : zz;
    }
    __syncthreads();

    half8 bf[4][4];
    f32x4 acc[2][4];

    // ---- GEMM1: z2 = relu(Z@W1+B1) ----
    #pragma unroll
    for (int ct4 = 0; ct4 < 4; ++ct4) {
        int ct = 4 * cw + ct4;
        #pragma unroll
        for (int kk = 0; kk < 4; ++kk)
            bf[ct4][kk] = *reinterpret_cast<const half8*>(
                Wt1 + (size_t)(16 * ct + m) * HD + kk * 32 + g * 8);
    }
    #pragma unroll
    for (int i = 0; i < 2; ++i)
        #pragma unroll
        for (int j = 0; j < 4; ++j) acc[i][j] = (f32x4){0.f, 0.f, 0.f, 0.f};
    #pragma unroll
    for (int rg2 = 0; rg2 < 2; ++rg2) {
        int rg = 2 * rw_ + rg2;           // 0..7 -> rows 0..127
        #pragma unroll
        for (int kk = 0; kk < 4; ++kk) {
            half8 a = *reinterpret_cast<const half8*>(
                &sA[(16 * rg + m) * PITCH + kk * 32 + g * 8]);
            #pragma unroll
            for (int ct4 = 0; ct4 < 4; ++ct4)
                acc[rg2][ct4] = __builtin_amdgcn_mfma_f32_16x16x32_f16(
                    a, bf[ct4][kk], acc[rg2][ct4], 0, 0, 0);
        }
    }
    __syncthreads();
    #pragma unroll
    for (int rg2 = 0; rg2 < 2; ++rg2) {
        int rg = 2 * rw_ + rg2;
        #pragma unroll
        for (int ct4 = 0; ct4 < 4; ++ct4) {
            int col = 16 * (4 * cw + ct4) + m;
            float bb = B1[col];
            #pragma unroll
            for (int reg = 0; reg < 4; ++reg) {
                int lr = 16 * rg + 4 * g + reg;
                sA[lr * PITCH + col] = (_Float16)fmaxf(acc[rg2][ct4][reg] + bb, 0.f);
            }
        }
    }
    __syncthreads();

    // ---- GEMM2: h = z2@W2+B2 ----
    #pragma unroll
    for (int ct4 = 0; ct4 < 4; ++ct4) {
        int ct = 4 * cw + ct4;
        #pragma unroll
        for (int kk = 0; kk < 4; ++kk)
            bf[ct4][kk] = *reinterpret_cast<const half8*>(
                Wt2 + (size_t)(16 * ct + m) * HD + kk * 32 + g * 8);
    }
    f32x4 acc2[2][4];
    #pragma unroll
    for (int i = 0; i < 2; ++i)
        #pragma unroll
        for (int j = 0; j < 4; ++j) acc2[i][j] = (f32x4){0.f, 0.f, 0.f, 0.f};
    #pragma unroll
    for (int rg2 = 0; rg2 < 2; ++rg2) {
        int rg = 2 * rw_ + rg2;
        #pragma unroll
        for (int kk = 0; kk < 4; ++kk) {
            half8 a = *reinterpret_cast<const half8*>(
                &sA[(16 * rg + m) * PITCH + kk * 32 + g * 8]);
            #pragma unroll
            for (int ct4 = 0; ct4 < 4; ++ct4)
                acc2[rg2][ct4] = __builtin_amdgcn_mfma_f32_16x16x32_f16(
                    a, bf[ct4][kk], acc2[rg2][ct4], 0, 0, 0);
        }
    }

    if (LAST) {
        // ---- fused readout: dot + 2-wave segmented scan + atomics ----
        #pragma unroll
        for (int rg2 = 0; rg2 < 2; ++rg2) {
            int rg = 2 * rw_ + rg2;
            float pr[4] = {0.f, 0.f, 0.f, 0.f};
            #pragma unroll
            for (int ct4 = 0; ct4 < 4; ++ct4) {
                int col = 16 * (4 * cw + ct4) + m;
                float bb = B2[col], rr = rw[col];
                #pragma unroll
                for (int reg = 0; reg < 4; ++reg)
                    pr[reg] = fmaf(acc2[rg2][ct4][reg] + bb, rr, pr[reg]);
            }
            #pragma unroll
            for (int reg = 0; reg < 4; ++reg) {
                #pragma unroll
                for (int d = 1; d < 16; d <<= 1) pr[reg] += __shfl_xor(pr[reg], d);
            }
            if (m == 0) {
                #pragma unroll
                for (int reg = 0; reg < 4; ++reg)
                    sD[16 * rg + 4 * g + reg][cw] = pr[reg];
            }
        }
        __syncthreads();
        if (t < 128) {                    // waves 0,1: rows 0..63 / 64..127
            int row = tile + t;
            float v = sD[t][0] + sD[t][1] + rb[0];
            int b = (row < n) ? batch[row] : -1;
            if (row >= n) v = 0.f;
            // per-wave segmented scan; wave-boundary / tile-boundary splits
            // are correct because both parts atomicAdd the same gout[b].
            #pragma unroll
            for (int d = 1; d < 64; d <<= 1) {
                int   ob = __shfl_up(b, d);
                float ov = __shfl_up(v, d);
                if (lane >= d && ob == b) v += ov;
            }
            int nb2 = __shfl_down(b, 1);
            bool lastl = (lane == 63) || (nb2 != b);
            if (lastl && b >= 0) atomicAdd(&gout[b], v);
        }
    } else {
        // ---- h back into sA, then GEMM3: h2' = relu(h@W3+B3) -> Y ----
        __syncthreads();
        #pragma unroll
        for (int rg2 = 0; rg2 < 2; ++rg2) {
            int rg = 2 * rw_ + rg2;
            #pragma unroll
            for (int ct4 = 0; ct4 < 4; ++ct4) {
                int col = 16 * (4 * cw + ct4) + m;
                float bb = B2[col];
                #pragma unroll
                for (int reg = 0; reg < 4; ++reg) {
                    int lr = 16 * rg + 4 * g + reg;
                    sA[lr * PITCH + col] = (_Float16)(acc2[rg2][ct4][reg] + bb);
                }
            }
        }
        __syncthreads();

        #pragma unroll
        for (int ct4 = 0; ct4 < 4; ++ct4) {
            int ct = 4 * cw + ct4;
            #pragma unroll
            for (int kk = 0; kk < 4; ++kk)
                bf[ct4][kk] = *reinterpret_cast<const half8*>(
                    Wt3 + (size_t)(16 * ct + m) * HD + kk * 32 + g * 8);
        }
        #pragma unroll
        for (int i = 0; i < 2; ++i)
            #pragma unroll
            for (int j = 0; j < 4; ++j) acc[i][j] = (f32x4){0.f, 0.f, 0.f, 0.f};
        #pragma unroll
        for (int rg2 = 0; rg2 < 2; ++rg2) {
            int rg = 2 * rw_ + rg2;
            #pragma unroll
            for (int kk = 0; kk < 4; ++kk) {
                half8 a = *reinterpret_cast<const half8*>(
                    &sA[(16 * rg + m) * PITCH + kk * 32 + g * 8]);
                #pragma unroll
                for (int ct4 = 0; ct4 < 4; ++ct4)
                    acc[rg2][ct4] = __builtin_amdgcn_mfma_f32_16x16x32_f16(
                        a, bf[ct4][kk], acc[rg2][ct4], 0, 0, 0);
            }
        }
        #pragma unroll
        for (int rg2 = 0; rg2 < 2; ++rg2) {
            int rg = 2 * rw_ + rg2;
            #pragma unroll
            for (int ct4 = 0; ct4 < 4; ++ct4) {
                int col = 16 * (4 * cw + ct4) + m;
                float bb = B3[col];
                #pragma unroll
                for (int reg = 0; reg < 4; ++reg) {
                    int r = tile + 16 * rg + 4 * g + reg;
                    if (r < n) {
                        float v = fmaxf(acc[rg2][ct4][reg] + bb, 0.f);
                        Y[(size_t)r * HD + col] = (_Float16)v;
                    }
                }
            }
        }
    }
}

// ---------------------------------------------------------------------------
extern "C" void kernel_launch(void* const* d_in, const int* in_sizes, int n_in,
                              void* d_out, int out_size, void* d_ws, size_t ws_size,
                              hipStream_t stream)
{
    const int N = in_sizes[0];
    const int E = in_sizes[1] / 2;
    const int G = out_size;

    const int*   x      = (const int*)d_in[0];
    const int*   ei     = (const int*)d_in[1];
    const int*   batch  = (const int*)d_in[2];
    const float* table  = (const float*)d_in[3];
    const float* bn_g   = (const float*)d_in[4];
    const float* bn_b   = (const float*)d_in[5];
    const float* bn_m   = (const float*)d_in[6];
    const float* bn_v   = (const float*)d_in[7];
    const float* lin_w  = (const float*)d_in[8];
    const float* lin_b  = (const float*)d_in[9];
    const float* epsv   = (const float*)d_in[10];
    const float* mlp_w1 = (const float*)d_in[11];
    const float* mlp_b1 = (const float*)d_in[12];
    const float* mbn_g  = (const float*)d_in[13];
    const float* mbn_b  = (const float*)d_in[14];
    const float* mbn_m  = (const float*)d_in[15];
    const float* mbn_v  = (const float*)d_in[16];
    const float* mlp_w2 = (const float*)d_in[17];
    const float* mlp_b2 = (const float*)d_in[18];
    const float* ro_w   = (const float*)d_in[19];
    const float* ro_b   = (const float*)d_in[20];

    const int* esrc_in = ei;
    const int* edst_in = ei + E;

    char* wsp = (char*)d_ws;
    size_t off = 0;
    auto alloc = [&](size_t bytes) {
        void* p = wsp + off;
        off += (bytes + 255) & ~(size_t)255;
        return p;
    };
    _Float16* bufA  = (_Float16*)alloc((size_t)N * HD * 2);  // z
    _Float16* bufB  = (_Float16*)alloc((size_t)N * HD * 2);  // h2
    _Float16* wtl   = (_Float16*)alloc((size_t)NLAYER * HD * HD * 2);
    _Float16* wt1   = (_Float16*)alloc((size_t)NLAYER * HD * HD * 2);
    _Float16* wt2   = (_Float16*)alloc((size_t)NLAYER * HD * HD * 2);
    float*    fbl   = (float*)alloc((size_t)NLAYER * HD * 4);
    float*    fb1   = (float*)alloc((size_t)NLAYER * HD * 4);
    int*      deg   = (int*)alloc((size_t)N * 4);
    int*      rowst = (int*)alloc((size_t)(N + 1) * 4);
    int*      cursor= (int*)alloc((size_t)N * 4);
    unsigned short* esrc = (unsigned short*)alloc((size_t)E * 2);
    int*      part  = (int*)alloc(1024 * 4);
    (void)ws_size;

    hipMemsetAsync(deg, 0, (size_t)N * 4, stream);
    hipMemsetAsync(d_out, 0, (size_t)G * 4, stream);

    // prep (3 blocks) + count_deg (chunks*8 blocks) in one launch
    const int npr = (N + 7) / 8;
    const int chunks = (E + EPB - 1) / EPB;
    prep_and_count<<<NLAYER + chunks * 8, 256, 0, stream>>>(
        bn_g, bn_b, bn_m, bn_v, lin_w, lin_b,
        mbn_g, mbn_b, mbn_m, mbn_v, mlp_w1, mlp_b1, mlp_w2,
        wtl, fbl, wt1, fb1, wt2,
        edst_in, deg, E, npr);

    int nb = (N + 1023) / 1024;
    scan_blocks<<<nb, 256, 0, stream>>>(deg, rowst, part, N);
    scan_add<<<(N + 255) / 256, 256, 0, stream>>>(rowst, cursor, part, nb, N, E);
    fill_csr<<<chunks * 8, 256, 0, stream>>>(esrc_in, edst_in, cursor, esrc, E, npr);

    const int gemm_grid   = (N + 63) / 64;
    const int gemm_grid2  = (N + 127) / 128;
    const int wave_grid   = (N + 3) / 4;

    // layer 0 lin (embed gather)
    lin_mfma<<<gemm_grid, 256, 0, stream>>>(table, x, wtl, fbl, bufB, N);

    for (int l = 0; l < NLAYER; ++l) {
        const _Float16* w1 = wt1 + (size_t)l * HD * HD;
        const float*    b1 = fb1 + (size_t)l * HD;
        const _Float16* w2 = wt2 + (size_t)l * HD * HD;
        const float*    b2 = mlp_b2 + (size_t)l * HD;

        aggregate_f16<<<wave_grid, 256, 0, stream>>>(
            bufB, rowst, esrc, epsv, l, bufA, N);

        if (l < NLAYER - 1) {
            const _Float16* w3 = wtl + (size_t)(l + 1) * HD * HD;
            const float*    b3 = fbl + (size_t)(l + 1) * HD;
            mlp3<false><<<gemm_grid2, 512, 0, stream>>>(
                bufA, w1, b1, w2, b2, w3, b3, bufB,
                nullptr, nullptr, nullptr, nullptr, N);
        } else {
            mlp3<true><<<gemm_grid2, 512, 0, stream>>>(
                bufA, w1, b1, w2, b2, nullptr, nullptr, nullptr,
                ro_w, ro_b, batch, (float*)d_out, N);
        }
    }
}

// Round 13
// 373.159 us; speedup vs baseline: 1.2423x; 1.0185x over previous
//
#include <hip/hip_runtime.h>
#include <hip/hip_fp16.h>

// ---------------------------------------------------------------------------
// GIN forward (eval mode), fp16-MFMA version.
// prep parallelized (24 transpose blocks + 3 bias blocks) and fused into the
// count_deg launch. CSR build XCD-range-partitioned, esrc u16.
// Pipeline:
//   prep_and_count -> scan_blocks -> scan_add -> fill_csr
//   lin_mfma (embed-gather + MFMA GEMM + relu -> h2_0)
//   per layer: aggregate_f16 (wave-per-node, readlane SGPR-base gathers)
//              mlp3 (128-row tile, 8 waves: GEMM1+relu -> GEMM2+b2 ->
//                    GEMM3+relu = next lin | last: fused readout)
// ---------------------------------------------------------------------------

#define HD 128
#define NLAYER 3
#define PITCH 136   // f16 units per LDS row (272 B)
#define EPB 2048    // edges per (chunk) block in CSR build
#define PREP_T 24   // transpose blocks: 3 layers x 8 col-groups
#define PREP_B (PREP_T + NLAYER)

typedef _Float16 half8 __attribute__((ext_vector_type(8)));
typedef float    f32x4 __attribute__((ext_vector_type(4)));

// -------- prep (blocks 0..26, parallelized) + count_deg (rest) -------------
__global__ void prep_and_count(
    const float* __restrict__ bn_g, const float* __restrict__ bn_b,
    const float* __restrict__ bn_m, const float* __restrict__ bn_v,
    const float* __restrict__ lin_w, const float* __restrict__ lin_b,
    const float* __restrict__ mbn_g, const float* __restrict__ mbn_b,
    const float* __restrict__ mbn_m, const float* __restrict__ mbn_v,
    const float* __restrict__ mlp_w1, const float* __restrict__ mlp_b1,
    const float* __restrict__ mlp_w2,
    _Float16* __restrict__ wtl, float* __restrict__ fbl,
    _Float16* __restrict__ wt1, float* __restrict__ fb1,
    _Float16* __restrict__ wt2,
    const int* __restrict__ dst, int* __restrict__ deg, int e, int npr)
{
    __shared__ float sa[HD], sc[HD], sa2[HD];
    const int t = threadIdx.x;

    if (blockIdx.x < PREP_T) {
        // transpose block: layer l, output columns [16*jg, 16*jg+16)
        const int l  = blockIdx.x >> 3;
        const int jg = blockIdx.x & 7;
        const int lb = l * HD;
        const int wb = l * HD * HD;
        if (t < HD) {
            sa[t]  = bn_g[lb + t] * rsqrtf(bn_v[lb + t] + 1e-5f);
            sa2[t] = mbn_g[lb + t] * rsqrtf(mbn_v[lb + t] + 1e-5f);
        }
        __syncthreads();
        const int k  = t & 127;
        const int jh = t >> 7;               // 2 columns per pass
        #pragma unroll
        for (int jj = 0; jj < 16; jj += 2) {
            int j = jg * 16 + jj + jh;
            wtl[wb + j * HD + k] = (_Float16)(sa[k]  * lin_w [wb + k * HD + j]);
            wt1[wb + j * HD + k] = (_Float16)(sa2[j] * mlp_w1[wb + k * HD + j]);
            wt2[wb + j * HD + k] = (_Float16)(          mlp_w2[wb + k * HD + j]);
        }
    } else if (blockIdx.x < PREP_B) {
        // bias-fold block: layer l
        const int l  = blockIdx.x - PREP_T;
        const int lb = l * HD;
        const int wb = l * HD * HD;
        if (t < HD) {
            float a = bn_g[lb + t] * rsqrtf(bn_v[lb + t] + 1e-5f);
            sc[t] = bn_b[lb + t] - bn_m[lb + t] * a;
        }
        __syncthreads();
        if (t < HD) {
            float a2 = mbn_g[lb + t] * rsqrtf(mbn_v[lb + t] + 1e-5f);
            float c2 = mbn_b[lb + t] - mbn_m[lb + t] * a2;
            float accb = lin_b[lb + t];
            for (int kk = 0; kk < HD; ++kk)
                accb += sc[kk] * lin_w[wb + kk * HD + t];   // coalesced, pipelined
            fbl[lb + t] = accb;
            fb1[lb + t] = a2 * mlp_b1[lb + t] + c2;
        }
    } else {
        int bid = blockIdx.x - PREP_B;
        int r = bid & 7;
        int chunk = bid >> 3;
        int lo = r * npr, hi = lo + npr;
        int base = chunk * EPB;
        int end = base + EPB; if (end > e) end = e;
        for (int i = base + t; i < end; i += 256) {
            int d = dst[i];
            if (d >= lo && d < hi) atomicAdd(&deg[d], 1);
        }
    }
}

__global__ void fill_csr(const int* __restrict__ src, const int* __restrict__ dst,
                         int* __restrict__ cursor,
                         unsigned short* __restrict__ esrc, int e, int npr)
{
    int r = blockIdx.x & 7;
    int chunk = blockIdx.x >> 3;
    int lo = r * npr, hi = lo + npr;
    int base = chunk * EPB;
    int end = base + EPB; if (end > e) end = e;
    for (int i = base + threadIdx.x; i < end; i += 256) {
        int d = dst[i];
        int s = src[i];
        if (d >= lo && d < hi) {
            int p = atomicAdd(&cursor[d], 1);
            esrc[p] = (unsigned short)s;
        }
    }
}

__global__ void scan_blocks(const int* __restrict__ deg, int* __restrict__ excl,
                            int* __restrict__ partials, int n)
{
    __shared__ int wt[4];
    int t = threadIdx.x;
    int base = blockIdx.x * 1024 + t * 4;
    int v0 = (base + 0 < n) ? deg[base + 0] : 0;
    int v1 = (base + 1 < n) ? deg[base + 1] : 0;
    int v2 = (base + 2 < n) ? deg[base + 2] : 0;
    int v3 = (base + 3 < n) ? deg[base + 3] : 0;
    int s = v0 + v1 + v2 + v3;
    int lane = t & 63, w = t >> 6;
    int inc = s;
    #pragma unroll
    for (int d = 1; d < 64; d <<= 1) {
        int o = __shfl_up(inc, d);
        if (lane >= d) inc += o;
    }
    if (lane == 63) wt[w] = inc;
    __syncthreads();
    int off = 0;
    for (int i = 0; i < w; ++i) off += wt[i];
    int ex = off + inc - s;
    if (base + 0 < n) excl[base + 0] = ex; ex += v0;
    if (base + 1 < n) excl[base + 1] = ex; ex += v1;
    if (base + 2 < n) excl[base + 2] = ex; ex += v2;
    if (base + 3 < n) excl[base + 3] = ex;
    if (t == 255) partials[blockIdx.x] = off + inc;
}

// scan_add with inlined partials-scan (nb <= 64)
__global__ void scan_add(int* __restrict__ rowst, int* __restrict__ cursor,
                         const int* __restrict__ partials, int nb, int n, int e)
{
    __shared__ int spfx[64];
    int t = threadIdx.x;
    if (t < 64) {
        int v = (t < nb) ? partials[t] : 0;
        int inc = v;
        #pragma unroll
        for (int d = 1; d < 64; d <<= 1) {
            int o = __shfl_up(inc, d);
            if (t >= d) inc += o;
        }
        spfx[t] = inc - v;
    }
    __syncthreads();
    int idx = blockIdx.x * blockDim.x + t;
    if (idx < n) {
        int v = rowst[idx] + spfx[idx >> 10];
        rowst[idx] = v;
        cursor[idx] = v;
    }
    if (idx == 0) rowst[n] = e;
}

// ---------------- lin_mfma: H2 = relu(embed[x] @ W + B) -> f16 (layer 0) ---
__global__ __launch_bounds__(256, 3)
void lin_mfma(const float* __restrict__ Xf, const int* __restrict__ xidx,
              const _Float16* __restrict__ Wt, const float* __restrict__ B,
              _Float16* __restrict__ Y, int n)
{
    __shared__ __align__(16) _Float16 sA[64 * PITCH];
    const int t = threadIdx.x;
    const int lane = t & 63;
    const int w = t >> 6;
    const int rw_ = w >> 1, cw = w & 1;
    const int m = lane & 15, g = lane >> 4;
    const int tile = blockIdx.x * 64;

    {
        int row = t >> 2, q = t & 3;
        int gr = tile + row;
        _Float16* dst = &sA[row * PITCH + q * 32];
        if (gr < n) {
            int id = xidx[gr];
            const float4* src = reinterpret_cast<const float4*>(Xf + (size_t)id * HD) + q * 8;
            #pragma unroll
            for (int c = 0; c < 4; ++c) {
                float4 va = src[2 * c], vb = src[2 * c + 1];
                half8 h = {(_Float16)va.x, (_Float16)va.y, (_Float16)va.z, (_Float16)va.w,
                           (_Float16)vb.x, (_Float16)vb.y, (_Float16)vb.z, (_Float16)vb.w};
                *reinterpret_cast<half8*>(dst + c * 8) = h;
            }
        } else {
            half8 zz = {0, 0, 0, 0, 0, 0, 0, 0};
            #pragma unroll
            for (int c = 0; c < 4; ++c) *reinterpret_cast<half8*>(dst + c * 8) = zz;
        }
    }
    __syncthreads();

    half8 bf[4][4];
    #pragma unroll
    for (int ct4 = 0; ct4 < 4; ++ct4) {
        int ct = 4 * cw + ct4;
        #pragma unroll
        for (int kk = 0; kk < 4; ++kk)
            bf[ct4][kk] = *reinterpret_cast<const half8*>(
                Wt + (size_t)(16 * ct + m) * HD + kk * 32 + g * 8);
    }

    f32x4 acc[2][4];
    #pragma unroll
    for (int i = 0; i < 2; ++i)
        #pragma unroll
        for (int j = 0; j < 4; ++j) acc[i][j] = (f32x4){0.f, 0.f, 0.f, 0.f};

    #pragma unroll
    for (int rg2 = 0; rg2 < 2; ++rg2) {
        int rg = 2 * rw_ + rg2;
        #pragma unroll
        for (int kk = 0; kk < 4; ++kk) {
            half8 a = *reinterpret_cast<const half8*>(
                &sA[(16 * rg + m) * PITCH + kk * 32 + g * 8]);
            #pragma unroll
            for (int ct4 = 0; ct4 < 4; ++ct4)
                acc[rg2][ct4] = __builtin_amdgcn_mfma_f32_16x16x32_f16(
                    a, bf[ct4][kk], acc[rg2][ct4], 0, 0, 0);
        }
    }

    #pragma unroll
    for (int rg2 = 0; rg2 < 2; ++rg2) {
        int rg = 2 * rw_ + rg2;
        #pragma unroll
        for (int ct4 = 0; ct4 < 4; ++ct4) {
            int col = 16 * (4 * cw + ct4) + m;
            float bb = B[col];
            #pragma unroll
            for (int reg = 0; reg < 4; ++reg) {
                int r = tile + 16 * rg + 4 * g + reg;
                if (r < n) {
                    float v = fmaxf(acc[rg2][ct4][reg] + bb, 0.f);
                    Y[(size_t)r * HD + col] = (_Float16)v;
                }
            }
        }
    }
}

// ---------------- aggregate: z = (1+eps)*h2 + sum in-edge h2[src], f16 -----
__global__ void aggregate_f16(const _Float16* __restrict__ h2,
                              const int* __restrict__ rowst,
                              const unsigned short* __restrict__ esrc,
                              const float* __restrict__ epsp,
                              int layer, _Float16* __restrict__ z, int n)
{
    int gw = (blockIdx.x * blockDim.x + threadIdx.x) >> 6;
    int lane = threadIdx.x & 63;
    if (gw >= n) return;
    float se = 1.0f + epsp[layer];
    int rs = __builtin_amdgcn_readfirstlane(rowst[gw]);
    int re = __builtin_amdgcn_readfirstlane(rowst[gw + 1]);
    const half2* hv = reinterpret_cast<const half2*>(h2);

    float2 own = __half22float2(hv[(size_t)gw * 64 + lane]);
    float ax[8], ay[8];
    ax[0] = se * own.x; ay[0] = se * own.y;
    #pragma unroll
    for (int k = 1; k < 8; ++k) { ax[k] = 0.f; ay[k] = 0.f; }

    for (int base = rs; base < re; base += 64) {
        int cnt = re - base; if (cnt > 64) cnt = 64;
        int eid = (base + lane < re) ? (int)esrc[base + lane] : 0;
        for (int j = 0; j < cnt; j += 16) {
            half2 t[16];
            #pragma unroll
            for (int k = 0; k < 16; ++k) {
                int idx = j + k; if (idx > cnt - 1) idx = cnt - 1;
                int sid = __builtin_amdgcn_readfirstlane(
                              __builtin_amdgcn_readlane(eid, idx));
                t[k] = hv[(size_t)sid * 64 + lane];
            }
            #pragma unroll
            for (int k = 0; k < 16; ++k) {
                if (j + k < cnt) {
                    float2 v = __half22float2(t[k]);
                    ax[k & 7] += v.x; ay[k & 7] += v.y;
                }
            }
        }
    }
    float ox = ((ax[0] + ax[1]) + (ax[2] + ax[3])) + ((ax[4] + ax[5]) + (ax[6] + ax[7]));
    float oy = ((ay[0] + ay[1]) + (ay[2] + ay[3])) + ((ay[4] + ay[5]) + (ay[6] + ay[7]));
    reinterpret_cast<half2*>(z)[(size_t)gw * 64 + lane] = __floats2half2_rn(ox, oy);
}

// ---------------- mlp3: triple-GEMM, 128-row tile, 8 waves -----------------
template<bool LAST>
__global__ __launch_bounds__(512)
void mlp3(const _Float16* __restrict__ Z,
          const _Float16* __restrict__ Wt1, const float* __restrict__ B1,
          const _Float16* __restrict__ Wt2, const float* __restrict__ B2,
          const _Float16* __restrict__ Wt3, const float* __restrict__ B3,
          _Float16* __restrict__ Y,
          const float* __restrict__ rw, const float* __restrict__ rb,
          const int* __restrict__ batch, float* __restrict__ gout, int n)
{
    __shared__ __align__(16) _Float16 sA[128 * PITCH];
    __shared__ float sD[128][2];
    const int t = threadIdx.x;            // 0..511
    const int lane = t & 63;
    const int w = t >> 6;                 // 0..7
    const int rw_ = w >> 1, cw = w & 1;   // 4 row-groups x 2 col-halves
    const int m = lane & 15, g = lane >> 4;
    const int tile = blockIdx.x * 128;

    {
        int row = t >> 2, q = t & 3;
        int gr = tile + row;
        _Float16* dst = &sA[row * PITCH + q * 32];
        half8 zz = {0, 0, 0, 0, 0, 0, 0, 0};
        const half8* src = reinterpret_cast<const half8*>(Z + (size_t)gr * HD + q * 32);
        #pragma unroll
        for (int c = 0; c < 4; ++c)
            *reinterpret_cast<half8*>(dst + c * 8) = (gr < n) ? src[c] : zz;
    }
    __syncthreads();

    half8 bf[4][4];
    f32x4 acc[2][4];

    // ---- GEMM1: z2 = relu(Z@W1+B1) ----
    #pragma unroll
    for (int ct4 = 0; ct4 < 4; ++ct4) {
        int ct = 4 * cw + ct4;
        #pragma unroll
        for (int kk = 0; kk < 4; ++kk)
            bf[ct4][kk] = *reinterpret_cast<const half8*>(
                Wt1 + (size_t)(16 * ct + m) * HD + kk * 32 + g * 8);
    }
    #pragma unroll
    for (int i = 0; i < 2; ++i)
        #pragma unroll
        for (int j = 0; j < 4; ++j) acc[i][j] = (f32x4){0.f, 0.f, 0.f, 0.f};
    #pragma unroll
    for (int rg2 = 0; rg2 < 2; ++rg2) {
        int rg = 2 * rw_ + rg2;
        #pragma unroll
        for (int kk = 0; kk < 4; ++kk) {
            half8 a = *reinterpret_cast<const half8*>(
                &sA[(16 * rg + m) * PITCH + kk * 32 + g * 8]);
            #pragma unroll
            for (int ct4 = 0; ct4 < 4; ++ct4)
                acc[rg2][ct4] = __builtin_amdgcn_mfma_f32_16x16x32_f16(
                    a, bf[ct4][kk], acc[rg2][ct4], 0, 0, 0);
        }
    }
    __syncthreads();
    #pragma unroll
    for (int rg2 = 0; rg2 < 2; ++rg2) {
        int rg = 2 * rw_ + rg2;
        #pragma unroll
        for (int ct4 = 0; ct4 < 4; ++ct4) {
            int col = 16 * (4 * cw + ct4) + m;
            float bb = B1[col];
            #pragma unroll
            for (int reg = 0; reg < 4; ++reg) {
                int lr = 16 * rg + 4 * g + reg;
                sA[lr * PITCH + col] = (_Float16)fmaxf(acc[rg2][ct4][reg] + bb, 0.f);
            }
        }
    }
    __syncthreads();

    // ---- GEMM2: h = z2@W2+B2 ----
    #pragma unroll
    for (int ct4 = 0; ct4 < 4; ++ct4) {
        int ct = 4 * cw + ct4;
        #pragma unroll
        for (int kk = 0; kk < 4; ++kk)
            bf[ct4][kk] = *reinterpret_cast<const half8*>(
                Wt2 + (size_t)(16 * ct + m) * HD + kk * 32 + g * 8);
    }
    f32x4 acc2[2][4];
    #pragma unroll
    for (int i = 0; i < 2; ++i)
        #pragma unroll
        for (int j = 0; j < 4; ++j) acc2[i][j] = (f32x4){0.f, 0.f, 0.f, 0.f};
    #pragma unroll
    for (int rg2 = 0; rg2 < 2; ++rg2) {
        int rg = 2 * rw_ + rg2;
        #pragma unroll
        for (int kk = 0; kk < 4; ++kk) {
            half8 a = *reinterpret_cast<const half8*>(
                &sA[(16 * rg + m) * PITCH + kk * 32 + g * 8]);
            #pragma unroll
            for (int ct4 = 0; ct4 < 4; ++ct4)
                acc2[rg2][ct4] = __builtin_amdgcn_mfma_f32_16x16x32_f16(
                    a, bf[ct4][kk], acc2[rg2][ct4], 0, 0, 0);
        }
    }

    if (LAST) {
        #pragma unroll
        for (int rg2 = 0; rg2 < 2; ++rg2) {
            int rg = 2 * rw_ + rg2;
            float pr[4] = {0.f, 0.f, 0.f, 0.f};
            #pragma unroll
            for (int ct4 = 0; ct4 < 4; ++ct4) {
                int col = 16 * (4 * cw + ct4) + m;
                float bb = B2[col], rr = rw[col];
                #pragma unroll
                for (int reg = 0; reg < 4; ++reg)
                    pr[reg] = fmaf(acc2[rg2][ct4][reg] + bb, rr, pr[reg]);
            }
            #pragma unroll
            for (int reg = 0; reg < 4; ++reg) {
                #pragma unroll
                for (int d = 1; d < 16; d <<= 1) pr[reg] += __shfl_xor(pr[reg], d);
            }
            if (m == 0) {
                #pragma unroll
                for (int reg = 0; reg < 4; ++reg)
                    sD[16 * rg + 4 * g + reg][cw] = pr[reg];
            }
        }
        __syncthreads();
        if (t < 128) {
            int row = tile + t;
            float v = sD[t][0] + sD[t][1] + rb[0];
            int b = (row < n) ? batch[row] : -1;
            if (row >= n) v = 0.f;
            #pragma unroll
            for (int d = 1; d < 64; d <<= 1) {
                int   ob = __shfl_up(b, d);
                float ov = __shfl_up(v, d);
                if (lane >= d && ob == b) v += ov;
            }
            int nb2 = __shfl_down(b, 1);
            bool lastl = (lane == 63) || (nb2 != b);
            if (lastl && b >= 0) atomicAdd(&gout[b], v);
        }
    } else {
        __syncthreads();
        #pragma unroll
        for (int rg2 = 0; rg2 < 2; ++rg2) {
            int rg = 2 * rw_ + rg2;
            #pragma unroll
            for (int ct4 = 0; ct4 < 4; ++ct4) {
                int col = 16 * (4 * cw + ct4) + m;
                float bb = B2[col];
                #pragma unroll
                for (int reg = 0; reg < 4; ++reg) {
                    int lr = 16 * rg + 4 * g + reg;
                    sA[lr * PITCH + col] = (_Float16)(acc2[rg2][ct4][reg] + bb);
                }
            }
        }
        __syncthreads();

        #pragma unroll
        for (int ct4 = 0; ct4 < 4; ++ct4) {
            int ct = 4 * cw + ct4;
            #pragma unroll
            for (int kk = 0; kk < 4; ++kk)
                bf[ct4][kk] = *reinterpret_cast<const half8*>(
                    Wt3 + (size_t)(16 * ct + m) * HD + kk * 32 + g * 8);
        }
        #pragma unroll
        for (int i = 0; i < 2; ++i)
            #pragma unroll
            for (int j = 0; j < 4; ++j) acc[i][j] = (f32x4){0.f, 0.f, 0.f, 0.f};
        #pragma unroll
        for (int rg2 = 0; rg2 < 2; ++rg2) {
            int rg = 2 * rw_ + rg2;
            #pragma unroll
            for (int kk = 0; kk < 4; ++kk) {
                half8 a = *reinterpret_cast<const half8*>(
                    &sA[(16 * rg + m) * PITCH + kk * 32 + g * 8]);
                #pragma unroll
                for (int ct4 = 0; ct4 < 4; ++ct4)
                    acc[rg2][ct4] = __builtin_amdgcn_mfma_f32_16x16x32_f16(
                        a, bf[ct4][kk], acc[rg2][ct4], 0, 0, 0);
            }
        }
        #pragma unroll
        for (int rg2 = 0; rg2 < 2; ++rg2) {
            int rg = 2 * rw_ + rg2;
            #pragma unroll
            for (int ct4 = 0; ct4 < 4; ++ct4) {
                int col = 16 * (4 * cw + ct4) + m;
                float bb = B3[col];
                #pragma unroll
                for (int reg = 0; reg < 4; ++reg) {
                    int r = tile + 16 * rg + 4 * g + reg;
                    if (r < n) {
                        float v = fmaxf(acc[rg2][ct4][reg] + bb, 0.f);
                        Y[(size_t)r * HD + col] = (_Float16)v;
                    }
                }
            }
        }
    }
}

// ---------------------------------------------------------------------------
extern "C" void kernel_launch(void* const* d_in, const int* in_sizes, int n_in,
                              void* d_out, int out_size, void* d_ws, size_t ws_size,
                              hipStream_t stream)
{
    const int N = in_sizes[0];
    const int E = in_sizes[1] / 2;
    const int G = out_size;

    const int*   x      = (const int*)d_in[0];
    const int*   ei     = (const int*)d_in[1];
    const int*   batch  = (const int*)d_in[2];
    const float* table  = (const float*)d_in[3];
    const float* bn_g   = (const float*)d_in[4];
    const float* bn_b   = (const float*)d_in[5];
    const float* bn_m   = (const float*)d_in[6];
    const float* bn_v   = (const float*)d_in[7];
    const float* lin_w  = (const float*)d_in[8];
    const float* lin_b  = (const float*)d_in[9];
    const float* epsv   = (const float*)d_in[10];
    const float* mlp_w1 = (const float*)d_in[11];
    const float* mlp_b1 = (const float*)d_in[12];
    const float* mbn_g  = (const float*)d_in[13];
    const float* mbn_b  = (const float*)d_in[14];
    const float* mbn_m  = (const float*)d_in[15];
    const float* mbn_v  = (const float*)d_in[16];
    const float* mlp_w2 = (const float*)d_in[17];
    const float* mlp_b2 = (const float*)d_in[18];
    const float* ro_w   = (const float*)d_in[19];
    const float* ro_b   = (const float*)d_in[20];

    const int* esrc_in = ei;
    const int* edst_in = ei + E;

    char* wsp = (char*)d_ws;
    size_t off = 0;
    auto alloc = [&](size_t bytes) {
        void* p = wsp + off;
        off += (bytes + 255) & ~(size_t)255;
        return p;
    };
    _Float16* bufA  = (_Float16*)alloc((size_t)N * HD * 2);  // z
    _Float16* bufB  = (_Float16*)alloc((size_t)N * HD * 2);  // h2
    _Float16* wtl   = (_Float16*)alloc((size_t)NLAYER * HD * HD * 2);
    _Float16* wt1   = (_Float16*)alloc((size_t)NLAYER * HD * HD * 2);
    _Float16* wt2   = (_Float16*)alloc((size_t)NLAYER * HD * HD * 2);
    float*    fbl   = (float*)alloc((size_t)NLAYER * HD * 4);
    float*    fb1   = (float*)alloc((size_t)NLAYER * HD * 4);
    int*      deg   = (int*)alloc((size_t)N * 4);
    int*      rowst = (int*)alloc((size_t)(N + 1) * 4);
    int*      cursor= (int*)alloc((size_t)N * 4);
    unsigned short* esrc = (unsigned short*)alloc((size_t)E * 2);
    int*      part  = (int*)alloc(1024 * 4);
    (void)ws_size;

    hipMemsetAsync(deg, 0, (size_t)N * 4, stream);
    hipMemsetAsync(d_out, 0, (size_t)G * 4, stream);

    // prep (27 parallel blocks) + count_deg (chunks*8 blocks) in one launch
    const int npr = (N + 7) / 8;
    const int chunks = (E + EPB - 1) / EPB;
    prep_and_count<<<PREP_B + chunks * 8, 256, 0, stream>>>(
        bn_g, bn_b, bn_m, bn_v, lin_w, lin_b,
        mbn_g, mbn_b, mbn_m, mbn_v, mlp_w1, mlp_b1, mlp_w2,
        wtl, fbl, wt1, fb1, wt2,
        edst_in, deg, E, npr);

    int nb = (N + 1023) / 1024;
    scan_blocks<<<nb, 256, 0, stream>>>(deg, rowst, part, N);
    scan_add<<<(N + 255) / 256, 256, 0, stream>>>(rowst, cursor, part, nb, N, E);
    fill_csr<<<chunks * 8, 256, 0, stream>>>(esrc_in, edst_in, cursor, esrc, E, npr);

    const int gemm_grid   = (N + 63) / 64;
    const int gemm_grid2  = (N + 127) / 128;
    const int wave_grid   = (N + 3) / 4;

    // layer 0 lin (embed gather)
    lin_mfma<<<gemm_grid, 256, 0, stream>>>(table, x, wtl, fbl, bufB, N);

    for (int l = 0; l < NLAYER; ++l) {
        const _Float16* w1 = wt1 + (size_t)l * HD * HD;
        const float*    b1 = fb1 + (size_t)l * HD;
        const _Float16* w2 = wt2 + (size_t)l * HD * HD;
        const float*    b2 = mlp_b2 + (size_t)l * HD;

        aggregate_f16<<<wave_grid, 256, 0, stream>>>(
            bufB, rowst, esrc, epsv, l, bufA, N);

        if (l < NLAYER - 1) {
            const _Float16* w3 = wtl + (size_t)(l + 1) * HD * HD;
            const float*    b3 = fbl + (size_t)(l + 1) * HD;
            mlp3<false><<<gemm_grid2, 512, 0, stream>>>(
                bufA, w1, b1, w2, b2, w3, b3, bufB,
                nullptr, nullptr, nullptr, nullptr, N);
        } else {
            mlp3<true><<<gemm_grid2, 512, 0, stream>>>(
                bufA, w1, b1, w2, b2, nullptr, nullptr, nullptr,
                ro_w, ro_b, batch, (float*)d_out, N);
        }
    }
}